// Round 8
// baseline (446.725 us; speedup 1.0000x reference)
//
#include <hip/hip_runtime.h>

#define N_GRAPHS_C 1000
#define NPG_C      100
#define N_EDGES_C  3200000
#define KTOP_C     30
#define CAP        4096      // per-graph edge-slot capacity (mean 3200, sigma ~57)

typedef _Float16 h2_t __attribute__((ext_vector_type(2)));

__device__ __forceinline__ float fdot2u(unsigned a, unsigned b, float c) {
#if __has_builtin(__builtin_amdgcn_fdot2)
    return __builtin_amdgcn_fdot2(__builtin_bit_cast(h2_t, a),
                                  __builtin_bit_cast(h2_t, b), c, false);
#else
    h2_t ha = __builtin_bit_cast(h2_t, a), hb = __builtin_bit_cast(h2_t, b);
    return fmaf((float)ha.x, (float)hb.x, fmaf((float)ha.y, (float)hb.y, c));
#endif
}

__device__ __forceinline__ unsigned packh2(float x, float y) {
    _Float16 hx = (_Float16)x, hy = (_Float16)y;
    return (unsigned)__builtin_bit_cast(unsigned short, hx) |
           ((unsigned)__builtin_bit_cast(unsigned short, hy) << 16);
}

__device__ __forceinline__ float ftanh(float x) {
    float e = __expf(2.0f * x);
    return 1.0f - 2.0f * __builtin_amdgcn_rcpf(e + 1.0f);
}

// ---------------- workspace layout (bytes) ----------------
// [0, 4096)            : gcur  int[1024]  (per-graph cursors; memset to 0)
// [4096, 4096+8.2MB)   : slots u16[1000*4096]  packed edges (d<<7 | s)

__global__ __launch_bounds__(1024)
void bucket_kernel(const int* __restrict__ src, const int* __restrict__ dst,
                   int* __restrict__ gcur, unsigned short* __restrict__ slots) {
    __shared__ int hist[N_GRAPHS_C];
    const int tid = threadIdx.x;
    const int base = blockIdx.x * 8192;
    for (int i = tid; i < N_GRAPHS_C; i += 1024) hist[i] = 0;
    __syncthreads();

    int g[8]; unsigned short pk[8]; bool v[8];
    #pragma unroll
    for (int k = 0; k < 8; ++k) {
        int e = base + tid + k * 1024;
        v[k] = false;
        if (e < N_EDGES_C) {
            int s = src[e], d = dst[e];
            if (s != d) {
                int gg = s / NPG_C;
                g[k] = gg;
                pk[k] = (unsigned short)(((d - gg * NPG_C) << 7) | (s - gg * NPG_C));
                v[k] = true;
                atomicAdd(&hist[gg], 1);
            }
        }
    }
    __syncthreads();
    for (int i = tid; i < N_GRAPHS_C; i += 1024) {
        int c = hist[i];
        hist[i] = atomicAdd(&gcur[i], c);
    }
    __syncthreads();
    #pragma unroll
    for (int k = 0; k < 8; ++k) {
        if (v[k]) {
            int pos = atomicAdd(&hist[g[k]], 1);
            if (pos < CAP) slots[g[k] * CAP + pos] = pk[k];
        }
    }
}

// ---------------- main per-graph kernel ----------------
// LDS (float offsets), total 9032 floats = 36,128 B -> 4 blocks/CU:
//  cntf  u32[100][52] (f16 pairs; first 2600 u32 = u8 scatter area) : [0, 5200)
//  planeH u32[32][52]                                   : [5200, 6864)
//  planeL u32[32][52]                                   : [6864, 8528)
//    (x-rows f32[100][32] and pooled[30][100] alias the 3328-word plane region)
//  dis f32[100]  : [8528, 8628)
//  t4  f32[100]  : [8628, 8728)
//  t4h u32[52]   : [8728, 8780)   t4l u32[52] : [8780, 8832)
//  sX4 f32[100]  : [8832, 8932)
//  srank int[100]: [8932, 9032)
//  tail s5/sP/s6/sO1/sFc/sZ (1728 floats) alias cntf region (dead after L4)
#define SMEM_FLOATS 9032

extern "C" __global__ __launch_bounds__(512, 8)
void dgcnn_kernel(const float* __restrict__ x,
                  const int* __restrict__ gcur, const unsigned short* __restrict__ slots,
                  const float* __restrict__ W1, const float* __restrict__ b1,
                  const float* __restrict__ W2, const float* __restrict__ b2,
                  const float* __restrict__ W3, const float* __restrict__ b3,
                  const float* __restrict__ W4, const float* __restrict__ b4,
                  const float* __restrict__ w5, const float* __restrict__ b5,
                  const float* __restrict__ w6, const float* __restrict__ b6,
                  const float* __restrict__ fw1, const float* __restrict__ fb1,
                  const float* __restrict__ fw2, const float* __restrict__ fb2,
                  float* __restrict__ out)
{
    extern __shared__ float sm[];
    unsigned* cntf   = (unsigned*)sm;          // 5200 u32 (f16 pairs)
    unsigned* cnt32  = (unsigned*)sm;          // first 2600 u32 = u8 scatter area
    unsigned* planeH = (unsigned*)(sm + 5200); // 1664
    unsigned* planeL = (unsigned*)(sm + 6864); // 1664
    float* xrows  = sm + 5200;                 // [100][32] aliases planes
    float* pooled = sm + 5200;                 // [30][100] aliases planes
    float* dis = sm + 8528;
    float* t4  = sm + 8628;
    unsigned* t4h = (unsigned*)(sm + 8728);
    unsigned* t4l = (unsigned*)(sm + 8780);
    float* sX4 = sm + 8832;
    int*   srank = (int*)(sm + 8932);
    float* s5  = sm;                           // tail aliases cntf region
    float* sP  = sm + 480;
    float* s6  = sm + 720;
    float* sO1 = sm + 1072;
    float* sFc = sm + 1200;
    float* sZ  = sm + 1712;

    const int tid = threadIdx.x;
    const int g   = blockIdx.x;
    const int f   = tid & 31;
    const int i0  = tid >> 5;                  // 0..15
    const int l64 = tid & 63;
    const int wv  = tid >> 6;                  // wave id 0..7

    const float* xg = x + (size_t)g * NPG_C * 128;

    // ---- P0: zero u8 scatter area ----
    for (int idx = tid; idx < 2600; idx += 512) cnt32[idx] = 0u;
    __syncthreads();

    // ---- P1: scatter u8 counts (packed u32 atomics; row stride 104 bytes) ----
    {
        int ec = gcur[g]; if (ec > CAP) ec = CAP;
        for (int k = tid; k < ec; k += 512) {
            unsigned e = slots[g * CAP + k];
            unsigned idx = (e >> 7) * 104 + (e & 127);
            atomicAdd(&cnt32[idx >> 2], 1u << ((idx & 3) * 8));
        }
    }
    __syncthreads();

    // ---- P2: dis = rsqrt(rowsum+1); read u8 words for in-place expansion ----
    unsigned ev[6];
    {
        #pragma unroll
        for (int k = 0; k < 6; ++k) {
            int w = tid + k * 512;
            ev[k] = (w < 2600) ? cnt32[w] : 0u;
        }
    }
    if (tid < 100) {
        const unsigned* rw = cnt32 + tid * 26;
        unsigned s = 0;
        #pragma unroll
        for (int k = 0; k < 26; ++k) {
            unsigned v = rw[k];
            s += (v & 0xffu) + ((v >> 8) & 0xffu) + ((v >> 16) & 0xffu) + (v >> 24);
        }
        dis[tid] = rsqrtf((float)s + 1.0f);
    }
    __syncthreads();

    // ---- P3: write f16-pair expansion (in place, 2x size) ----
    {
        #pragma unroll
        for (int k = 0; k < 6; ++k) {
            int w = tid + k * 512;
            if (w < 2600) {
                unsigned v = ev[k];
                int i = w / 26, c = w - i * 26;
                int dst = i * 52 + c * 2;
                cntf[dst]     = packh2((float)(v & 255u), (float)((v >> 8) & 255u));
                cntf[dst + 1] = packh2((float)((v >> 16) & 255u), (float)(v >> 24));
            }
        }
    }
    __syncthreads();

    // ---- split v into f16 hi/lo planes, pair via cross-half shfl ----
#define STORE_PLANES(VV)                                                            \
    {                                                                               \
        _Pragma("unroll")                                                           \
        for (int r = 0; r < 7; ++r) {                                               \
            int i = i0 + (r << 4);                                                  \
            float v_ = (i < 100) ? VV[r] : 0.f;                                     \
            _Float16 hh = (_Float16)v_;                                             \
            float rem = v_ - (float)hh;                                             \
            _Float16 hl = (_Float16)rem;                                            \
            unsigned uh = __builtin_bit_cast(unsigned short, hh);                   \
            unsigned ul = __builtin_bit_cast(unsigned short, hl);                   \
            unsigned ph = (unsigned)__shfl((int)uh, l64 | 32, 64);                  \
            unsigned pl2 = (unsigned)__shfl((int)ul, l64 | 32, 64);                 \
            if (l64 < 32 && i < 100) {                                              \
                int p = wv + (r << 3);                                              \
                planeH[f * 52 + p] = uh | (ph << 16);                               \
                planeL[f * 52 + p] = ul | (pl2 << 16);                              \
            }                                                                       \
        }                                                                           \
        if (tid < 64) {                                                             \
            int f2 = tid & 31, pw = 50 + (tid >> 5);                                \
            planeH[f2 * 52 + pw] = 0u; planeL[f2 * 52 + pw] = 0u;                   \
        }                                                                           \
    }

    float xr1[7], xr2[7], xr3[7], sc[7], vv[7], tt[7];

    // ---- P4: L1 = X @ W1 (128->32); store Td1 planes; sc = Td1 own value ----
    {
        float acc[7] = {0,0,0,0,0,0,0};
        for (int c4 = 0; c4 < 128; c4 += 4) {
            float w0 = W1[(c4+0)*32+f], w1 = W1[(c4+1)*32+f];
            float w2 = W1[(c4+2)*32+f], w3 = W1[(c4+3)*32+f];
            #pragma unroll
            for (int r = 0; r < 7; ++r) {
                int i = i0 + (r << 4);
                if (i < 100) {
                    const float4 xv = *(const float4*)&xg[i*128 + c4];
                    acc[r] = fmaf(xv.x,w0, fmaf(xv.y,w1, fmaf(xv.z,w2, fmaf(xv.w,w3, acc[r]))));
                }
            }
        }
        #pragma unroll
        for (int r = 0; r < 7; ++r) {
            int i = i0 + (r << 4);
            vv[r] = (i < 100) ? acc[r] * dis[i] : 0.f;
            sc[r] = vv[r];
        }
        STORE_PLANES(vv);
    }
    __syncthreads();

    // ---- AGG via dot2: acc = sum_k cnt16 . (Thi + Tlo); out = tanh(dis*(acc+sc)+b) ----
#define AGG_DOT(XR, BIAS)                                                           \
    {                                                                               \
        float acc[7] = {0,0,0,0,0,0,0};                                             \
        const unsigned* hp = planeH + f * 52;                                       \
        const unsigned* lp = planeL + f * 52;                                       \
        for (int kc = 0; kc < 13; ++kc) {                                           \
            uint4 th = *(const uint4*)&hp[kc*4];                                    \
            uint4 tl = *(const uint4*)&lp[kc*4];                                    \
            _Pragma("unroll")                                                       \
            for (int r = 0; r < 7; ++r) {                                           \
                int i = i0 + (r << 4);                                              \
                if (i < 100) {                                                      \
                    uint4 cw = *(const uint4*)&cntf[i*52 + kc*4];                   \
                    acc[r] = fdot2u(cw.x, th.x, acc[r]);                            \
                    acc[r] = fdot2u(cw.y, th.y, acc[r]);                            \
                    acc[r] = fdot2u(cw.z, th.z, acc[r]);                            \
                    acc[r] = fdot2u(cw.w, th.w, acc[r]);                            \
                    acc[r] = fdot2u(cw.x, tl.x, acc[r]);                            \
                    acc[r] = fdot2u(cw.y, tl.y, acc[r]);                            \
                    acc[r] = fdot2u(cw.z, tl.z, acc[r]);                            \
                    acc[r] = fdot2u(cw.w, tl.w, acc[r]);                            \
                }                                                                   \
            }                                                                       \
        }                                                                           \
        float bf_ = BIAS[f];                                                        \
        _Pragma("unroll")                                                           \
        for (int r = 0; r < 7; ++r) {                                               \
            int i = i0 + (r << 4);                                                  \
            if (i < 100) XR[r] = ftanh(dis[i] * (acc[r] + sc[r]) + bf_);            \
        }                                                                           \
    }

#define STORE_ROWS(XR)                                                              \
    {                                                                               \
        _Pragma("unroll")                                                           \
        for (int r = 0; r < 7; ++r) { int i = i0 + (r << 4); if (i < 100) xrows[i*32 + f] = XR[r]; } \
    }

#define XW32(TT, W)                                                                 \
    {                                                                               \
        _Pragma("unroll")                                                           \
        for (int r = 0; r < 7; ++r) TT[r] = 0.f;                                    \
        for (int c4 = 0; c4 < 32; c4 += 4) {                                        \
            float w0 = W[(c4+0)*32+f], w1 = W[(c4+1)*32+f];                         \
            float w2 = W[(c4+2)*32+f], w3 = W[(c4+3)*32+f];                         \
            _Pragma("unroll")                                                       \
            for (int r = 0; r < 7; ++r) {                                           \
                int i = i0 + (r << 4);                                              \
                if (i < 100) {                                                      \
                    const float4 xv = *(const float4*)&xrows[i*32 + c4];            \
                    TT[r] = fmaf(xv.x,w0, fmaf(xv.y,w1, fmaf(xv.z,w2, fmaf(xv.w,w3, TT[r])))); \
                }                                                                   \
            }                                                                       \
        }                                                                           \
    }

#define SCALE_STORE(TT)                                                             \
    {                                                                               \
        _Pragma("unroll")                                                           \
        for (int r = 0; r < 7; ++r) {                                               \
            int i = i0 + (r << 4);                                                  \
            vv[r] = (i < 100) ? TT[r] * dis[i] : 0.f;                               \
            sc[r] = vv[r];                                                          \
        }                                                                           \
        STORE_PLANES(vv);                                                           \
    }

    AGG_DOT(xr1, b1);          // P5
    __syncthreads();
    STORE_ROWS(xr1);           // P6 (x1 rows over dead planes)
    __syncthreads();
    XW32(tt, W2);              // P7
    __syncthreads();
    SCALE_STORE(tt);           // P8 (Td2 planes over dead x-rows)
    __syncthreads();
    AGG_DOT(xr2, b2);          // P9
    __syncthreads();
    STORE_ROWS(xr2);
    __syncthreads();
    XW32(tt, W3);
    __syncthreads();
    SCALE_STORE(tt);
    __syncthreads();
    AGG_DOT(xr3, b3);          // x3 lives in registers only

    // ---- L4 (32->1): t4[i] = dis_i * (x3 row . W4) via shfl reduce ----
    {
        float w4f = W4[f];
        #pragma unroll
        for (int r = 0; r < 7; ++r) {
            int i = i0 + (r << 4);
            float v = (i < 100) ? xr3[r] * w4f : 0.f;
            #pragma unroll
            for (int off = 16; off >= 1; off >>= 1) v += __shfl_xor(v, off, 32);
            if (f == 0 && i < 100) t4[i] = v * dis[i];
        }
    }
    __syncthreads();

    // ---- pack t4 into f16 hi/lo pairs; zero srank ----
    if (tid < 52) {
        float a = (2*tid < 100) ? t4[2*tid] : 0.f;
        float b = (2*tid+1 < 100) ? t4[2*tid+1] : 0.f;
        _Float16 ah = (_Float16)a, bh = (_Float16)b;
        float ar = a - (float)ah, br = b - (float)bh;
        t4h[tid] = (unsigned)__builtin_bit_cast(unsigned short, ah) |
                   ((unsigned)__builtin_bit_cast(unsigned short, bh) << 16);
        t4l[tid] = packh2(ar, br);
    }
    if (tid < 100) srank[tid] = 0;
    __syncthreads();

    // ---- L4 dot (dot2) + tanh (exact: sort keys) ----
    if (tid < 100) {
        float acc = 0.f;
        const unsigned* cr = cntf + tid * 52;
        for (int kc = 0; kc < 13; ++kc) {
            uint4 cw = *(const uint4*)&cr[kc*4];
            uint4 th = *(const uint4*)&t4h[kc*4];
            uint4 tl = *(const uint4*)&t4l[kc*4];
            acc = fdot2u(cw.x, th.x, acc);
            acc = fdot2u(cw.y, th.y, acc);
            acc = fdot2u(cw.z, th.z, acc);
            acc = fdot2u(cw.w, th.w, acc);
            acc = fdot2u(cw.x, tl.x, acc);
            acc = fdot2u(cw.y, tl.y, acc);
            acc = fdot2u(cw.z, tl.z, acc);
            acc = fdot2u(cw.w, tl.w, acc);
        }
        sX4[tid] = tanhf(dis[tid] * (acc + t4[tid]) + b4[0]);
    }
    __syncthreads();

    // ---- SortAggregation rank, wave-parallel (500 threads, 20 cmp each) ----
    if (tid < 500) {
        int i = tid / 5, seg = tid - i * 5;
        float vi = sX4[i];
        int c = 0;
        int jb = seg * 20;
        #pragma unroll
        for (int jo = 0; jo < 20; ++jo) {
            int j = jb + jo;
            float vj = sX4[j];
            c += (vj > vi) || (vj == vi && j < i);
        }
        atomicAdd(&srank[i], c);
    }
    __syncthreads();

    // ---- gather top-30 rows into pooled[30][100] ----
    #pragma unroll
    for (int r = 0; r < 7; ++r) {
        int i = i0 + (r << 4);
        if (i < 100) {
            int rk = srank[i];
            if (rk < KTOP_C) {
                float* pr = pooled + rk * 100;
                pr[f]      = xr1[r];
                pr[32 + f] = xr2[r];
                pr[64 + f] = xr3[r];
                if (f == 0) pr[96] = sX4[i];
            }
        }
    }
    __syncthreads();

    // ---- conv5 (97 -> 16) + ReLU ----
    if (tid < 480) {
        int l = tid >> 4, co = tid & 15;
        const float* pr = pooled + l * 100;
        const float* wr = w5 + co * 97;
        float acc = b5[co];
        for (int c4 = 0; c4 < 96; c4 += 4) {
            const float4 pv = *(const float4*)&pr[c4];
            acc = fmaf(pv.x, wr[c4+0], fmaf(pv.y, wr[c4+1], fmaf(pv.z, wr[c4+2], fmaf(pv.w, wr[c4+3], acc))));
        }
        acc = fmaf(pr[96], wr[96], acc);
        s5[co * 30 + l] = fmaxf(acc, 0.f);
    }
    __syncthreads();

    // ---- maxpool(2,2): [16][30] -> [16][15] ----
    if (tid < 240) {
        int co = tid / 15, j = tid - co * 15;
        sP[co * 15 + j] = fmaxf(s5[co * 30 + 2*j], s5[co * 30 + 2*j + 1]);
    }
    __syncthreads();

    // ---- conv6 (16 -> 32, k=5) + ReLU: [32][11] ----
    if (tid < 352) {
        int co = tid / 11, l = tid - co * 11;
        float acc = b6[co];
        for (int ci = 0; ci < 16; ++ci) {
            const float* wr = w6 + (co * 16 + ci) * 5;
            const float* pr = sP + ci * 15 + l;
            acc = fmaf(wr[0], pr[0], fmaf(wr[1], pr[1], fmaf(wr[2], pr[2],
                  fmaf(wr[3], pr[3], fmaf(wr[4], pr[4], acc)))));
        }
        s6[co * 11 + l] = fmaxf(acc, 0.f);
    }
    __syncthreads();

    // ---- fc1 (352 -> 128) + ReLU ----
    {
        int j = tid & 127, part = tid >> 7;
        int ibeg = part * 88, iend = ibeg + 88;
        float acc = (part == 0) ? fb1[j] : 0.f;
        for (int i = ibeg; i < iend; ++i)
            acc = fmaf(s6[i], fw1[i * 128 + j], acc);
        sFc[part * 128 + j] = acc;
    }
    __syncthreads();
    if (tid < 128) {
        float v = sFc[tid] + sFc[128 + tid] + sFc[256 + tid] + sFc[384 + tid];
        sO1[tid] = fmaxf(v, 0.f);
    }
    __syncthreads();

    // ---- fc2 (128 -> 10) + log_softmax ----
    if (tid < 10) {
        float acc = fb2[tid];
        for (int k = 0; k < 128; ++k)
            acc = fmaf(sO1[k], fw2[k * 10 + tid], acc);
        sZ[tid] = acc;
    }
    __syncthreads();
    if (tid < 10) {
        float m = sZ[0];
        for (int c = 1; c < 10; ++c) m = fmaxf(m, sZ[c]);
        float se = 0.f;
        for (int c = 0; c < 10; ++c) se += expf(sZ[c] - m);
        out[g * 10 + tid] = sZ[tid] - m - logf(se);
    }
}

extern "C" void kernel_launch(void* const* d_in, const int* in_sizes, int n_in,
                              void* d_out, int out_size, void* d_ws, size_t ws_size,
                              hipStream_t stream) {
    const float* x   = (const float*)d_in[0];
    const int*   ei  = (const int*)d_in[1];
    const int*   src = ei;
    const int*   dst = ei + N_EDGES_C;
    const float* W1 = (const float*)d_in[3];  const float* b1 = (const float*)d_in[4];
    const float* W2 = (const float*)d_in[5];  const float* b2 = (const float*)d_in[6];
    const float* W3 = (const float*)d_in[7];  const float* b3 = (const float*)d_in[8];
    const float* W4 = (const float*)d_in[9];  const float* b4 = (const float*)d_in[10];
    const float* w5 = (const float*)d_in[11]; const float* b5 = (const float*)d_in[12];
    const float* w6 = (const float*)d_in[13]; const float* b6 = (const float*)d_in[14];
    const float* fw1 = (const float*)d_in[15]; const float* fb1 = (const float*)d_in[16];
    const float* fw2 = (const float*)d_in[17]; const float* fb2 = (const float*)d_in[18];
    float* out = (float*)d_out;

    int* gcur = (int*)d_ws;
    unsigned short* slots = (unsigned short*)((char*)d_ws + 4096);

    hipMemsetAsync(gcur, 0, 4096, stream);

    bucket_kernel<<<(N_EDGES_C + 8191) / 8192, 1024, 0, stream>>>(src, dst, gcur, slots);

    size_t smem = (size_t)SMEM_FLOATS * sizeof(float);  // 36,128 B -> 4 blocks/CU
    hipFuncSetAttribute((const void*)dgcnn_kernel,
                        hipFuncAttributeMaxDynamicSharedMemorySize, (int)smem);
    dgcnn_kernel<<<N_GRAPHS_C, 512, smem, stream>>>(
        x, gcur, slots, W1, b1, W2, b2, W3, b3, W4, b4,
        w5, b5, w6, b6, fw1, fb1, fw2, fb2, out);
}

// Round 9
// 191.581 us; speedup vs baseline: 2.3318x; 2.3318x over previous
//
#include <hip/hip_runtime.h>

#define N_GRAPHS_C 1000
#define NPG_C      100
#define N_EDGES_C  3200000
#define KTOP_C     30
#define CAP        4096      // per-graph edge-slot capacity (mean 3200, sigma ~57)

typedef _Float16 h2_t __attribute__((ext_vector_type(2)));

__device__ __forceinline__ float fdot2u(unsigned a, unsigned b, float c) {
#if __has_builtin(__builtin_amdgcn_fdot2)
    return __builtin_amdgcn_fdot2(__builtin_bit_cast(h2_t, a),
                                  __builtin_bit_cast(h2_t, b), c, false);
#else
    h2_t ha = __builtin_bit_cast(h2_t, a), hb = __builtin_bit_cast(h2_t, b);
    return fmaf((float)ha.x, (float)hb.x, fmaf((float)ha.y, (float)hb.y, c));
#endif
}

__device__ __forceinline__ unsigned packh2(float x, float y) {
    _Float16 hx = (_Float16)x, hy = (_Float16)y;
    return (unsigned)__builtin_bit_cast(unsigned short, hx) |
           ((unsigned)__builtin_bit_cast(unsigned short, hy) << 16);
}

__device__ __forceinline__ float ftanh(float x) {
    float e = __expf(2.0f * x);
    return 1.0f - 2.0f * __builtin_amdgcn_rcpf(e + 1.0f);
}

// ---------------- workspace layout (bytes) ----------------
// [0, 4096)            : gcur  int[1024]  (per-graph cursors; memset to 0)
// [4096, 4096+8.2MB)   : slots u16[1000*4096]  packed edges (d<<7 | s)

__global__ __launch_bounds__(1024)
void bucket_kernel(const int* __restrict__ src, const int* __restrict__ dst,
                   int* __restrict__ gcur, unsigned short* __restrict__ slots) {
    __shared__ int hist[N_GRAPHS_C];
    const int tid = threadIdx.x;
    const int base = blockIdx.x * 8192;
    for (int i = tid; i < N_GRAPHS_C; i += 1024) hist[i] = 0;
    __syncthreads();

    int g[8]; unsigned short pk[8]; bool v[8];
    #pragma unroll
    for (int k = 0; k < 8; ++k) {
        int e = base + tid + k * 1024;
        v[k] = false;
        if (e < N_EDGES_C) {
            int s = src[e], d = dst[e];
            if (s != d) {
                int gg = s / NPG_C;
                g[k] = gg;
                pk[k] = (unsigned short)(((d - gg * NPG_C) << 7) | (s - gg * NPG_C));
                v[k] = true;
                atomicAdd(&hist[gg], 1);
            }
        }
    }
    __syncthreads();
    for (int i = tid; i < N_GRAPHS_C; i += 1024) {
        int c = hist[i];
        hist[i] = atomicAdd(&gcur[i], c);
    }
    __syncthreads();
    #pragma unroll
    for (int k = 0; k < 8; ++k) {
        if (v[k]) {
            int pos = atomicAdd(&hist[g[k]], 1);
            if (pos < CAP) slots[g[k] * CAP + pos] = pk[k];
        }
    }
}

// ---------------- main per-graph kernel ----------------
// LDS (float offsets), total 12232 floats = 48,928 B -> 3 blocks/CU:
//  cntf  u32[100][52] (f16 pairs; first 2600 u32 = u8 scatter area) : [0, 5200)
//  planeH u32[32][52]                                  : [5200, 6864)
//  planeL u32[32][52]                                  : [6864, 8528)
//  xrows f32[100][32] (pooled[30][100] aliases)        : [8528, 11728)
//  dis f32[100]  : [11728, 11828)
//  t4  f32[100]  : [11828, 11928)
//  t4h u32[52]   : [11928, 11980)   t4l u32[52] : [11980, 12032)
//  sX4 f32[100]  : [12032, 12132)
//  srank int[100]: [12132, 12232)
//  tail s5/sP/s6/sO1/sFc/sZ (1728 floats) alias cntf region (dead after L4 dot)
#define SMEM_FLOATS 12232

extern "C" __global__ __launch_bounds__(512, 4)
void dgcnn_kernel(const float* __restrict__ x,
                  const int* __restrict__ gcur, const unsigned short* __restrict__ slots,
                  const float* __restrict__ W1, const float* __restrict__ b1,
                  const float* __restrict__ W2, const float* __restrict__ b2,
                  const float* __restrict__ W3, const float* __restrict__ b3,
                  const float* __restrict__ W4, const float* __restrict__ b4,
                  const float* __restrict__ w5, const float* __restrict__ b5,
                  const float* __restrict__ w6, const float* __restrict__ b6,
                  const float* __restrict__ fw1, const float* __restrict__ fb1,
                  const float* __restrict__ fw2, const float* __restrict__ fb2,
                  float* __restrict__ out)
{
    extern __shared__ float sm[];
    unsigned* cntf   = (unsigned*)sm;          // 5200 u32 (f16 pairs)
    unsigned* cnt32  = (unsigned*)sm;          // first 2600 u32 = u8 scatter area
    unsigned* planeH = (unsigned*)(sm + 5200); // 1664
    unsigned* planeL = (unsigned*)(sm + 6864); // 1664
    float* xrows  = sm + 8528;                 // [100][32]
    float* pooled = sm + 8528;                 // [30][100] aliases xrows (dead)
    float* dis = sm + 11728;
    float* t4  = sm + 11828;
    unsigned* t4h = (unsigned*)(sm + 11928);
    unsigned* t4l = (unsigned*)(sm + 11980);
    float* sX4 = sm + 12032;
    int*   srank = (int*)(sm + 12132);
    float* s5  = sm;                           // tail aliases cntf region
    float* sP  = sm + 480;
    float* s6  = sm + 720;
    float* sO1 = sm + 1072;
    float* sFc = sm + 1200;
    float* sZ  = sm + 1712;

    const int tid = threadIdx.x;
    const int g   = blockIdx.x;
    const int f   = tid & 31;
    const int i0  = tid >> 5;                  // 0..15
    const int l64 = tid & 63;
    const int wv  = tid >> 6;                  // wave id 0..7

    const float* xg = x + (size_t)g * NPG_C * 128;

    // ---- P0: zero u8 scatter area ----
    for (int idx = tid; idx < 2600; idx += 512) cnt32[idx] = 0u;
    __syncthreads();

    // ---- P1: scatter u8 counts (packed u32 atomics; row stride 104 bytes) ----
    {
        int ec = gcur[g]; if (ec > CAP) ec = CAP;
        for (int k = tid; k < ec; k += 512) {
            unsigned e = slots[g * CAP + k];
            unsigned idx = (e >> 7) * 104 + (e & 127);
            atomicAdd(&cnt32[idx >> 2], 1u << ((idx & 3) * 8));
        }
    }
    __syncthreads();

    // ---- P2: dis = rsqrt(rowsum+1); stage u8 words in regs for expansion ----
    unsigned ev[6];
    {
        #pragma unroll
        for (int k = 0; k < 6; ++k) {
            int w = tid + k * 512;
            ev[k] = (w < 2600) ? cnt32[w] : 0u;
        }
    }
    if (tid < 100) {
        const unsigned* rw = cnt32 + tid * 26;
        unsigned s = 0;
        #pragma unroll
        for (int k = 0; k < 26; ++k) {
            unsigned v = rw[k];
            s += (v & 0xffu) + ((v >> 8) & 0xffu) + ((v >> 16) & 0xffu) + (v >> 24);
        }
        dis[tid] = rsqrtf((float)s + 1.0f);
    }
    __syncthreads();

    // ---- P3: write f16-pair expansion (in place, 2x size) ----
    {
        #pragma unroll
        for (int k = 0; k < 6; ++k) {
            int w = tid + k * 512;
            if (w < 2600) {
                unsigned v = ev[k];
                int i = w / 26, c = w - i * 26;
                int dst = i * 52 + c * 2;
                cntf[dst]     = packh2((float)(v & 255u), (float)((v >> 8) & 255u));
                cntf[dst + 1] = packh2((float)((v >> 16) & 255u), (float)(v >> 24));
            }
        }
    }
    __syncthreads();

    // ---- split v into f16 hi/lo planes, pair via cross-half shfl ----
#define STORE_PLANES(VV)                                                            \
    {                                                                               \
        _Pragma("unroll")                                                           \
        for (int r = 0; r < 7; ++r) {                                               \
            int i = i0 + (r << 4);                                                  \
            float v_ = (i < 100) ? VV[r] : 0.f;                                     \
            _Float16 hh = (_Float16)v_;                                             \
            float rem = v_ - (float)hh;                                             \
            _Float16 hl = (_Float16)rem;                                            \
            unsigned uh = __builtin_bit_cast(unsigned short, hh);                   \
            unsigned ul = __builtin_bit_cast(unsigned short, hl);                   \
            unsigned ph = (unsigned)__shfl((int)uh, l64 | 32, 64);                  \
            unsigned pl2 = (unsigned)__shfl((int)ul, l64 | 32, 64);                 \
            if (l64 < 32 && i < 100) {                                              \
                int p = wv + (r << 3);                                              \
                planeH[f * 52 + p] = uh | (ph << 16);                               \
                planeL[f * 52 + p] = ul | (pl2 << 16);                              \
            }                                                                       \
        }                                                                           \
        if (tid < 64) {                                                             \
            int f2 = tid & 31, pw = 50 + (tid >> 5);                                \
            planeH[f2 * 52 + pw] = 0u; planeL[f2 * 52 + pw] = 0u;                   \
        }                                                                           \
    }

    float xr1[7], xr2[7], xr3[7], sc[7], vv[7], tt[7];

    // ---- P4: L1 = X @ W1 (128->32); store Td1 planes; sc = Td1 own value ----
    {
        float acc[7] = {0,0,0,0,0,0,0};
        for (int c4 = 0; c4 < 128; c4 += 4) {
            float w0 = W1[(c4+0)*32+f], w1 = W1[(c4+1)*32+f];
            float w2 = W1[(c4+2)*32+f], w3 = W1[(c4+3)*32+f];
            #pragma unroll
            for (int r = 0; r < 7; ++r) {
                int i = i0 + (r << 4);
                if (i < 100) {
                    const float4 xv = *(const float4*)&xg[i*128 + c4];
                    acc[r] = fmaf(xv.x,w0, fmaf(xv.y,w1, fmaf(xv.z,w2, fmaf(xv.w,w3, acc[r]))));
                }
            }
        }
        #pragma unroll
        for (int r = 0; r < 7; ++r) {
            int i = i0 + (r << 4);
            vv[r] = (i < 100) ? acc[r] * dis[i] : 0.f;
            sc[r] = vv[r];
        }
        STORE_PLANES(vv);
    }
    __syncthreads();

    // ---- AGG via dot2: acc = sum_k cnt16 . (Thi + Tlo); tanh epilogue; optional
    //      direct write of x rows into xrows (separate region -> race-free) ----
#define AGG_DOT(XR, BIAS, WRITE_X)                                                  \
    {                                                                               \
        float acc[7] = {0,0,0,0,0,0,0};                                             \
        const unsigned* hp = planeH + f * 52;                                       \
        const unsigned* lp = planeL + f * 52;                                       \
        for (int kc = 0; kc < 13; ++kc) {                                           \
            uint4 th = *(const uint4*)&hp[kc*4];                                    \
            uint4 tl = *(const uint4*)&lp[kc*4];                                    \
            _Pragma("unroll")                                                       \
            for (int r = 0; r < 7; ++r) {                                           \
                int i = i0 + (r << 4);                                              \
                if (i < 100) {                                                      \
                    uint4 cw = *(const uint4*)&cntf[i*52 + kc*4];                   \
                    acc[r] = fdot2u(cw.x, th.x, acc[r]);                            \
                    acc[r] = fdot2u(cw.y, th.y, acc[r]);                            \
                    acc[r] = fdot2u(cw.z, th.z, acc[r]);                            \
                    acc[r] = fdot2u(cw.w, th.w, acc[r]);                            \
                    acc[r] = fdot2u(cw.x, tl.x, acc[r]);                            \
                    acc[r] = fdot2u(cw.y, tl.y, acc[r]);                            \
                    acc[r] = fdot2u(cw.z, tl.z, acc[r]);                            \
                    acc[r] = fdot2u(cw.w, tl.w, acc[r]);                            \
                }                                                                   \
            }                                                                       \
        }                                                                           \
        float bf_ = BIAS[f];                                                        \
        _Pragma("unroll")                                                           \
        for (int r = 0; r < 7; ++r) {                                               \
            int i = i0 + (r << 4);                                                  \
            if (i < 100) {                                                          \
                XR[r] = ftanh(dis[i] * (acc[r] + sc[r]) + bf_);                     \
                if (WRITE_X) xrows[i*32 + f] = XR[r];                               \
            }                                                                       \
        }                                                                           \
    }

    // ---- XW + scale + plane store, single phase (reads xrows, writes planes) ----
#define XW_STORE(W)                                                                 \
    {                                                                               \
        _Pragma("unroll")                                                           \
        for (int r = 0; r < 7; ++r) tt[r] = 0.f;                                    \
        for (int c4 = 0; c4 < 32; c4 += 4) {                                        \
            float w0 = W[(c4+0)*32+f], w1 = W[(c4+1)*32+f];                         \
            float w2 = W[(c4+2)*32+f], w3 = W[(c4+3)*32+f];                         \
            _Pragma("unroll")                                                       \
            for (int r = 0; r < 7; ++r) {                                           \
                int i = i0 + (r << 4);                                              \
                if (i < 100) {                                                      \
                    const float4 xv = *(const float4*)&xrows[i*32 + c4];            \
                    tt[r] = fmaf(xv.x,w0, fmaf(xv.y,w1, fmaf(xv.z,w2, fmaf(xv.w,w3, tt[r])))); \
                }                                                                   \
            }                                                                       \
        }                                                                           \
        _Pragma("unroll")                                                           \
        for (int r = 0; r < 7; ++r) {                                               \
            int i = i0 + (r << 4);                                                  \
            vv[r] = (i < 100) ? tt[r] * dis[i] : 0.f;                               \
            sc[r] = vv[r];                                                          \
        }                                                                           \
        STORE_PLANES(vv);                                                           \
    }

    AGG_DOT(xr1, b1, 1);       // reads planes/cntf, writes xrows
    __syncthreads();
    XW_STORE(W2);              // reads xrows, writes planes
    __syncthreads();
    AGG_DOT(xr2, b2, 1);
    __syncthreads();
    XW_STORE(W3);
    __syncthreads();
    AGG_DOT(xr3, b3, 0);       // x3 lives in registers only

    // ---- L4 (32->1): t4[i] = dis_i * (x3 row . W4) via shfl reduce ----
    {
        float w4f = W4[f];
        #pragma unroll
        for (int r = 0; r < 7; ++r) {
            int i = i0 + (r << 4);
            float v = (i < 100) ? xr3[r] * w4f : 0.f;
            #pragma unroll
            for (int off = 16; off >= 1; off >>= 1) v += __shfl_xor(v, off, 32);
            if (f == 0 && i < 100) t4[i] = v * dis[i];
        }
    }
    __syncthreads();

    // ---- pack t4 into f16 hi/lo pairs; zero srank ----
    if (tid < 52) {
        float a = (2*tid < 100) ? t4[2*tid] : 0.f;
        float b = (2*tid+1 < 100) ? t4[2*tid+1] : 0.f;
        _Float16 ah = (_Float16)a, bh = (_Float16)b;
        float ar = a - (float)ah, br = b - (float)bh;
        t4h[tid] = (unsigned)__builtin_bit_cast(unsigned short, ah) |
                   ((unsigned)__builtin_bit_cast(unsigned short, bh) << 16);
        t4l[tid] = packh2(ar, br);
    }
    if (tid < 100) srank[tid] = 0;
    __syncthreads();

    // ---- L4 dot (dot2) + tanh (sort keys) ----
    if (tid < 100) {
        float acc = 0.f;
        const unsigned* cr = cntf + tid * 52;
        for (int kc = 0; kc < 13; ++kc) {
            uint4 cw = *(const uint4*)&cr[kc*4];
            uint4 th = *(const uint4*)&t4h[kc*4];
            uint4 tl = *(const uint4*)&t4l[kc*4];
            acc = fdot2u(cw.x, th.x, acc);
            acc = fdot2u(cw.y, th.y, acc);
            acc = fdot2u(cw.z, th.z, acc);
            acc = fdot2u(cw.w, th.w, acc);
            acc = fdot2u(cw.x, tl.x, acc);
            acc = fdot2u(cw.y, tl.y, acc);
            acc = fdot2u(cw.z, tl.z, acc);
            acc = fdot2u(cw.w, tl.w, acc);
        }
        sX4[tid] = tanhf(dis[tid] * (acc + t4[tid]) + b4[0]);
    }
    __syncthreads();

    // ---- SortAggregation rank, wave-parallel (500 threads, 20 cmp each) ----
    if (tid < 500) {
        int i = tid / 5, seg = tid - i * 5;
        float vi = sX4[i];
        int c = 0;
        int jb = seg * 20;
        #pragma unroll
        for (int jo = 0; jo < 20; ++jo) {
            int j = jb + jo;
            float vj = sX4[j];
            c += (vj > vi) || (vj == vi && j < i);
        }
        atomicAdd(&srank[i], c);
    }
    __syncthreads();

    // ---- gather top-30 rows into pooled[30][100] (aliases dead xrows) ----
    #pragma unroll
    for (int r = 0; r < 7; ++r) {
        int i = i0 + (r << 4);
        if (i < 100) {
            int rk = srank[i];
            if (rk < KTOP_C) {
                float* pr = pooled + rk * 100;
                pr[f]      = xr1[r];
                pr[32 + f] = xr2[r];
                pr[64 + f] = xr3[r];
                if (f == 0) pr[96] = sX4[i];
            }
        }
    }
    __syncthreads();

    // ---- conv5 (97 -> 16) + ReLU ----
    if (tid < 480) {
        int l = tid >> 4, co = tid & 15;
        const float* pr = pooled + l * 100;
        const float* wr = w5 + co * 97;
        float acc = b5[co];
        for (int c4 = 0; c4 < 96; c4 += 4) {
            const float4 pv = *(const float4*)&pr[c4];
            acc = fmaf(pv.x, wr[c4+0], fmaf(pv.y, wr[c4+1], fmaf(pv.z, wr[c4+2], fmaf(pv.w, wr[c4+3], acc))));
        }
        acc = fmaf(pr[96], wr[96], acc);
        s5[co * 30 + l] = fmaxf(acc, 0.f);
    }
    __syncthreads();

    // ---- maxpool(2,2): [16][30] -> [16][15] ----
    if (tid < 240) {
        int co = tid / 15, j = tid - co * 15;
        sP[co * 15 + j] = fmaxf(s5[co * 30 + 2*j], s5[co * 30 + 2*j + 1]);
    }
    __syncthreads();

    // ---- conv6 (16 -> 32, k=5) + ReLU: [32][11] ----
    if (tid < 352) {
        int co = tid / 11, l = tid - co * 11;
        float acc = b6[co];
        for (int ci = 0; ci < 16; ++ci) {
            const float* wr = w6 + (co * 16 + ci) * 5;
            const float* pr = sP + ci * 15 + l;
            acc = fmaf(wr[0], pr[0], fmaf(wr[1], pr[1], fmaf(wr[2], pr[2],
                  fmaf(wr[3], pr[3], fmaf(wr[4], pr[4], acc)))));
        }
        s6[co * 11 + l] = fmaxf(acc, 0.f);
    }
    __syncthreads();

    // ---- fc1 (352 -> 128) + ReLU ----
    {
        int j = tid & 127, part = tid >> 7;
        int ibeg = part * 88, iend = ibeg + 88;
        float acc = (part == 0) ? fb1[j] : 0.f;
        for (int i = ibeg; i < iend; ++i)
            acc = fmaf(s6[i], fw1[i * 128 + j], acc);
        sFc[part * 128 + j] = acc;
    }
    __syncthreads();
    if (tid < 128) {
        float v = sFc[tid] + sFc[128 + tid] + sFc[256 + tid] + sFc[384 + tid];
        sO1[tid] = fmaxf(v, 0.f);
    }
    __syncthreads();

    // ---- fc2 (128 -> 10) + log_softmax ----
    if (tid < 10) {
        float acc = fb2[tid];
        for (int k = 0; k < 128; ++k)
            acc = fmaf(sO1[k], fw2[k * 10 + tid], acc);
        sZ[tid] = acc;
    }
    __syncthreads();
    if (tid < 10) {
        float m = sZ[0];
        for (int c = 1; c < 10; ++c) m = fmaxf(m, sZ[c]);
        float se = 0.f;
        for (int c = 0; c < 10; ++c) se += expf(sZ[c] - m);
        out[g * 10 + tid] = sZ[tid] - m - logf(se);
    }
}

extern "C" void kernel_launch(void* const* d_in, const int* in_sizes, int n_in,
                              void* d_out, int out_size, void* d_ws, size_t ws_size,
                              hipStream_t stream) {
    const float* x   = (const float*)d_in[0];
    const int*   ei  = (const int*)d_in[1];
    const int*   src = ei;
    const int*   dst = ei + N_EDGES_C;
    const float* W1 = (const float*)d_in[3];  const float* b1 = (const float*)d_in[4];
    const float* W2 = (const float*)d_in[5];  const float* b2 = (const float*)d_in[6];
    const float* W3 = (const float*)d_in[7];  const float* b3 = (const float*)d_in[8];
    const float* W4 = (const float*)d_in[9];  const float* b4 = (const float*)d_in[10];
    const float* w5 = (const float*)d_in[11]; const float* b5 = (const float*)d_in[12];
    const float* w6 = (const float*)d_in[13]; const float* b6 = (const float*)d_in[14];
    const float* fw1 = (const float*)d_in[15]; const float* fb1 = (const float*)d_in[16];
    const float* fw2 = (const float*)d_in[17]; const float* fb2 = (const float*)d_in[18];
    float* out = (float*)d_out;

    int* gcur = (int*)d_ws;
    unsigned short* slots = (unsigned short*)((char*)d_ws + 4096);

    hipMemsetAsync(gcur, 0, 4096, stream);

    bucket_kernel<<<(N_EDGES_C + 8191) / 8192, 1024, 0, stream>>>(src, dst, gcur, slots);

    size_t smem = (size_t)SMEM_FLOATS * sizeof(float);  // 48,928 B -> 3 blocks/CU
    hipFuncSetAttribute((const void*)dgcnn_kernel,
                        hipFuncAttributeMaxDynamicSharedMemorySize, (int)smem);
    dgcnn_kernel<<<N_GRAPHS_C, 512, smem, stream>>>(
        x, gcur, slots, W1, b1, W2, b2, W3, b3, W4, b4,
        w5, b5, w6, b6, fw1, fb1, fw2, fb2, out);
}

// Round 10
// 169.815 us; speedup vs baseline: 2.6307x; 1.1282x over previous
//
#include <hip/hip_runtime.h>

#define N_GRAPHS_C 1000
#define NPG_C      100
#define N_EDGES_C  3200000
#define KTOP_C     30
#define CAP        4096      // per-graph edge-slot capacity (mean 3200, sigma ~57)

typedef _Float16 f16x8 __attribute__((ext_vector_type(8)));
typedef float    f32x4 __attribute__((ext_vector_type(4)));
typedef _Float16 h2_t  __attribute__((ext_vector_type(2)));

__device__ __forceinline__ float fdot2u(unsigned a, unsigned b, float c) {
#if __has_builtin(__builtin_amdgcn_fdot2)
    return __builtin_amdgcn_fdot2(__builtin_bit_cast(h2_t, a),
                                  __builtin_bit_cast(h2_t, b), c, false);
#else
    h2_t ha = __builtin_bit_cast(h2_t, a), hb = __builtin_bit_cast(h2_t, b);
    return fmaf((float)ha.x, (float)hb.x, fmaf((float)ha.y, (float)hb.y, c));
#endif
}

__device__ __forceinline__ unsigned packh2(float x, float y) {
    _Float16 hx = (_Float16)x, hy = (_Float16)y;
    return (unsigned)__builtin_bit_cast(unsigned short, hx) |
           ((unsigned)__builtin_bit_cast(unsigned short, hy) << 16);
}

__device__ __forceinline__ float f16b(unsigned v) {
    return (float)__builtin_bit_cast(_Float16, (unsigned short)v);
}

__device__ __forceinline__ float ftanh(float x) {
    float e = __expf(2.0f * x);
    return 1.0f - 2.0f * __builtin_amdgcn_rcpf(e + 1.0f);
}

// ---------------- workspace layout (bytes) ----------------
// [0, 4096)            : gcur  int[1024]  (memset to 0)
// [4096, 4096+8.2MB)   : slots u16[1000*4096]  packed edges (d<<7 | s)

__global__ __launch_bounds__(1024)
void bucket_kernel(const int* __restrict__ src, const int* __restrict__ dst,
                   int* __restrict__ gcur, unsigned short* __restrict__ slots) {
    __shared__ int hist[N_GRAPHS_C];
    const int tid = threadIdx.x;
    const int base = blockIdx.x * 8192;
    for (int i = tid; i < N_GRAPHS_C; i += 1024) hist[i] = 0;
    __syncthreads();

    int g[8]; unsigned short pk[8]; bool v[8];
    #pragma unroll
    for (int k = 0; k < 8; ++k) {
        int e = base + tid + k * 1024;
        v[k] = false;
        if (e < N_EDGES_C) {
            int s = src[e], d = dst[e];
            if (s != d) {
                int gg = s / NPG_C;
                g[k] = gg;
                pk[k] = (unsigned short)(((d - gg * NPG_C) << 7) | (s - gg * NPG_C));
                v[k] = true;
                atomicAdd(&hist[gg], 1);
            }
        }
    }
    __syncthreads();
    for (int i = tid; i < N_GRAPHS_C; i += 1024) {
        int c = hist[i];
        hist[i] = atomicAdd(&gcur[i], c);
    }
    __syncthreads();
    #pragma unroll
    for (int k = 0; k < 8; ++k) {
        if (v[k]) {
            int pos = atomicAdd(&hist[g[k]], 1);
            if (pos < CAP) slots[g[k] * CAP + pos] = pk[k];
        }
    }
}

// ---------------- main per-graph kernel ----------------
// LDS (u32 word offsets), total 15712 words = 62,848 B -> 2 blocks/CU:
//  cntP   [0, 7616)      f16 cnt matrix, 112 rows x 68 words (128-f16 k-pad, banks spread)
//  planes [7616, 11968)  Td hi/lo: p{0,1} x n{0..31} x 68 words; scatter u8 area = first 2600
//  xrows  [11968, 15168) f32[100][32]; pooled[30][100] aliases after GCN
//  dis    [15168, 15280) f32[112] (pads 0)
//  t4     [15280, 15384) f32[104]
//  t4h    [15384, 15448) t4l [15448, 15512)
//  sX4    [15512, 15612) srank [15612, 15712)
//  tail s5/sP/s6/sO1/sFc/sZ (1728 f32) aliases cntP (dead after L4 dot)
#define SMEM_WORDS 15712

extern "C" __global__ __launch_bounds__(512, 4)
void dgcnn_kernel(const float* __restrict__ x,
                  const int* __restrict__ gcur, const unsigned short* __restrict__ slots,
                  const float* __restrict__ W1, const float* __restrict__ b1,
                  const float* __restrict__ W2, const float* __restrict__ b2,
                  const float* __restrict__ W3, const float* __restrict__ b3,
                  const float* __restrict__ W4, const float* __restrict__ b4,
                  const float* __restrict__ w5, const float* __restrict__ b5,
                  const float* __restrict__ w6, const float* __restrict__ b6,
                  const float* __restrict__ fw1, const float* __restrict__ fb1,
                  const float* __restrict__ fw2, const float* __restrict__ fb2,
                  float* __restrict__ out)
{
    extern __shared__ unsigned smu[];
    unsigned* cntP   = smu;                    // 7616
    unsigned* planes = smu + 7616;             // 4352 (scatter area = first 2600)
    float* xrows  = (float*)(smu + 11968);     // 3200
    float* pooled = xrows;
    float* dis = (float*)(smu + 15168);        // 112
    float* t4  = (float*)(smu + 15280);        // 104
    unsigned* t4h = smu + 15384;               // 64
    unsigned* t4l = smu + 15448;               // 64
    float* sX4 = (float*)(smu + 15512);        // 100
    int*   srank = (int*)(smu + 15612);        // 100
    float* s5  = (float*)smu;                  // tail aliases cntP
    float* sPb = s5 + 480;
    float* s6  = s5 + 720;
    float* sO1 = s5 + 1072;
    float* sFc = s5 + 1200;
    float* sZ  = s5 + 1712;

    const int tid = threadIdx.x;
    const int g   = blockIdx.x;
    const int f   = tid & 31;
    const int i0  = tid >> 5;                  // 0..15
    const int l64 = tid & 63;
    const int wv  = tid >> 6;                  // 0..7

    const float* xg = x + (size_t)g * NPG_C * 128;

    // ---- P0: zero cntP + planes (incl. scatter area & all pads); dis pads ----
    for (int idx = tid; idx < 11968; idx += 512) smu[idx] = 0u;
    if (tid < 12) dis[100 + tid] = 0.f;
    __syncthreads();

    // ---- P1: scatter u8 counts into planes-region (u8[100][104]) ----
    {
        int ec = gcur[g]; if (ec > CAP) ec = CAP;
        for (int k = tid; k < ec; k += 512) {
            unsigned e = slots[g * CAP + k];
            unsigned idx = (e >> 7) * 104 + (e & 127);
            atomicAdd(&planes[idx >> 2], 1u << ((idx & 3) * 8));
        }
    }
    __syncthreads();

    // ---- P2: dis = rsqrt(rowsum+1) ----
    if (tid < 100) {
        const unsigned* rw = planes + tid * 26;
        unsigned s = 0;
        #pragma unroll
        for (int k = 0; k < 26; ++k) {
            unsigned v = rw[k];
            s += (v & 0xffu) + ((v >> 8) & 0xffu) + ((v >> 16) & 0xffu) + (v >> 24);
        }
        dis[tid] = rsqrtf((float)s + 1.0f);
    }
    __syncthreads();

    // ---- P3: expand u8 counts -> f16 pairs in cntP (disjoint regions) ----
    #pragma unroll
    for (int k = 0; k < 6; ++k) {
        int w = tid + k * 512;
        if (w < 2600) {
            unsigned v = planes[w];
            int i = w / 26, c = w - i * 26;
            int d = i * 68 + c * 2;
            cntP[d]     = packh2((float)(v & 255u), (float)((v >> 8) & 255u));
            cntP[d + 1] = packh2((float)((v >> 16) & 255u), (float)(v >> 24));
        }
    }
    __syncthreads();

    // ---- paired hi/lo f16 plane store: thread (i0,f) value v for row i=i0+16r ----
    auto storePlanes = [&](float v, int r) {
        _Float16 hh = (_Float16)v; float rem = v - (float)hh; _Float16 hl = (_Float16)rem;
        unsigned uh = __builtin_bit_cast(unsigned short, hh);
        unsigned ul = __builtin_bit_cast(unsigned short, hl);
        unsigned ph = (unsigned)__shfl((int)uh, l64 | 32, 64);
        unsigned pl = (unsigned)__shfl((int)ul, l64 | 32, 64);
        int i = i0 + (r << 4);
        if (l64 < 32 && i < 100) {
            int wd = wv + (r << 3);                   // = i>>1 < 50
            planes[f * 68 + wd]        = uh | (ph << 16);
            planes[2176 + f * 68 + wd] = ul | (pl << 16);
        }
    };

    // ---- P4: zero plane pad words; L1 = X @ W1; store Td1 planes ----
    for (int idx = tid; idx < 1152; idx += 512) {
        int rw = idx / 18, wd = idx - rw * 18;
        planes[rw * 68 + 50 + wd] = 0u;
    }
    {
        float acc[7] = {0,0,0,0,0,0,0};
        for (int c4 = 0; c4 < 128; c4 += 4) {
            float w0 = W1[(c4+0)*32+f], w1 = W1[(c4+1)*32+f];
            float w2 = W1[(c4+2)*32+f], w3 = W1[(c4+3)*32+f];
            #pragma unroll
            for (int r = 0; r < 7; ++r) {
                int i = i0 + (r << 4);
                if (i < 100) {
                    const float4 xv = *(const float4*)&xg[i*128 + c4];
                    acc[r] = fmaf(xv.x,w0, fmaf(xv.y,w1, fmaf(xv.z,w2, fmaf(xv.w,w3, acc[r]))));
                }
            }
        }
        #pragma unroll
        for (int r = 0; r < 7; ++r) {
            int i = i0 + (r << 4);
            float v = (i < 100) ? acc[r] * dis[i] : 0.f;
            storePlanes(v, r);
        }
    }
    __syncthreads();

    // ---- AGG via MFMA: waves 0-6, wave wv owns rows 16wv..16wv+15 ----
    // A: cnt f16 (row = l&15 within tile, k = (l>>4)*8+i); B: planes [n][k], col = l&15.
    auto AGG = [&](f32x4& fa, f32x4& fb, const float* Bp, bool wx) {
        if (wv < 7) {
            f32x4 a0 = {0.f,0.f,0.f,0.f}, a1 = {0.f,0.f,0.f,0.f};
            const unsigned* ab = cntP + ((wv << 4) + (l64 & 15)) * 68 + ((l64 >> 4) << 2);
            const unsigned* bb = planes + (l64 & 15) * 68 + ((l64 >> 4) << 2);
            #pragma unroll
            for (int p = 0; p < 2; ++p) {
                const unsigned* bp = bb + p * 2176;
                #pragma unroll
                for (int ks = 0; ks < 4; ++ks) {
                    f16x8 av = __builtin_bit_cast(f16x8, *(const uint4*)(ab + ks*16));
                    f16x8 b0 = __builtin_bit_cast(f16x8, *(const uint4*)(bp + ks*16));
                    f16x8 b1 = __builtin_bit_cast(f16x8, *(const uint4*)(bp + 16*68 + ks*16));
                    a0 = __builtin_amdgcn_mfma_f32_16x16x32_f16(av, b0, a0, 0, 0, 0);
                    a1 = __builtin_amdgcn_mfma_f32_16x16x32_f16(av, b1, a1, 0, 0, 0);
                }
            }
            int n0 = l64 & 15, r0 = (wv << 4) + ((l64 >> 4) << 2);
            uint2 sh0 = *(const uint2*)(planes + n0 * 68 + (r0 >> 1));
            uint2 sl0 = *(const uint2*)(planes + 2176 + n0 * 68 + (r0 >> 1));
            uint2 sh1 = *(const uint2*)(planes + (16 + n0) * 68 + (r0 >> 1));
            uint2 sl1 = *(const uint2*)(planes + 2176 + (16 + n0) * 68 + (r0 >> 1));
            float4 dv = *(const float4*)&dis[r0];
            float bi0 = Bp[n0], bi1 = Bp[16 + n0];
            #pragma unroll
            for (int j = 0; j < 4; ++j) {
                unsigned sft = (unsigned)((j & 1) * 16);
                float sc0 = f16b(((j < 2) ? sh0.x : sh0.y) >> sft) +
                            f16b(((j < 2) ? sl0.x : sl0.y) >> sft);
                float sc1 = f16b(((j < 2) ? sh1.x : sh1.y) >> sft) +
                            f16b(((j < 2) ? sl1.x : sl1.y) >> sft);
                float d_ = (j == 0) ? dv.x : (j == 1) ? dv.y : (j == 2) ? dv.z : dv.w;
                float v0 = ftanh(d_ * (a0[j] + sc0) + bi0);
                float v1 = ftanh(d_ * (a1[j] + sc1) + bi1);
                fa[j] = v0; fb[j] = v1;
                if (wx) {
                    int row = r0 + j;
                    if (row < 100) { xrows[row*32 + n0] = v0; xrows[row*32 + 16 + n0] = v1; }
                }
            }
        }
    };

    // ---- XW: T = xrows @ W (fp32 VALU), scale by dis, store hi/lo planes ----
    auto XW = [&](const float* W) {
        float ttl[7];
        #pragma unroll
        for (int r = 0; r < 7; ++r) ttl[r] = 0.f;
        for (int c4 = 0; c4 < 32; c4 += 4) {
            float w0 = W[(c4+0)*32+f], w1 = W[(c4+1)*32+f];
            float w2 = W[(c4+2)*32+f], w3 = W[(c4+3)*32+f];
            #pragma unroll
            for (int r = 0; r < 7; ++r) {
                int i = i0 + (r << 4);
                if (i < 100) {
                    const float4 xv = *(const float4*)&xrows[i*32 + c4];
                    ttl[r] = fmaf(xv.x,w0, fmaf(xv.y,w1, fmaf(xv.z,w2, fmaf(xv.w,w3, ttl[r]))));
                }
            }
        }
        #pragma unroll
        for (int r = 0; r < 7; ++r) {
            int i = i0 + (r << 4);
            float v = (i < 100) ? ttl[r] * dis[i] : 0.f;
            storePlanes(v, r);
        }
    };

    f32x4 f1a, f1b, f2a, f2b, f3a, f3b;

    AGG(f1a, f1b, b1, true);   __syncthreads();
    XW(W2);                    __syncthreads();
    AGG(f2a, f2b, b2, true);   __syncthreads();
    XW(W3);                    __syncthreads();
    AGG(f3a, f3b, b3, false);

    // ---- L4 (32->1) from x3 frags via 16-lane shfl reduce ----
    if (wv < 7) {
        float w4a = W4[l64 & 15], w4b = W4[16 + (l64 & 15)];
        int r0 = (wv << 4) + ((l64 >> 4) << 2);
        #pragma unroll
        for (int j = 0; j < 4; ++j) {
            float v = f3a[j] * w4a + f3b[j] * w4b;
            v += __shfl_xor(v, 1, 16); v += __shfl_xor(v, 2, 16);
            v += __shfl_xor(v, 4, 16); v += __shfl_xor(v, 8, 16);
            int row = r0 + j;
            if ((l64 & 15) == 0 && row < 100) t4[row] = v * dis[row];
        }
    }
    if (tid < 100) srank[tid] = 0;
    __syncthreads();

    // ---- pack t4 hi/lo (64 words, pads zero) ----
    if (tid < 64) {
        float a = (2*tid < 100) ? t4[2*tid] : 0.f;
        float b = (2*tid+1 < 100) ? t4[2*tid+1] : 0.f;
        _Float16 ah = (_Float16)a, bh = (_Float16)b;
        t4h[tid] = (unsigned)__builtin_bit_cast(unsigned short, ah) |
                   ((unsigned)__builtin_bit_cast(unsigned short, bh) << 16);
        t4l[tid] = packh2(a - (float)ah, b - (float)bh);
    }
    __syncthreads();

    // ---- L4 dot (dot2 over cntP rows) + exact tanh (sort keys) ----
    if (tid < 100) {
        float acc = 0.f;
        const unsigned* cr = cntP + tid * 68;
        for (int kc = 0; kc < 16; ++kc) {
            uint4 cw = *(const uint4*)&cr[kc*4];
            uint4 th = *(const uint4*)&t4h[kc*4];
            uint4 tl = *(const uint4*)&t4l[kc*4];
            acc = fdot2u(cw.x, th.x, acc);
            acc = fdot2u(cw.y, th.y, acc);
            acc = fdot2u(cw.z, th.z, acc);
            acc = fdot2u(cw.w, th.w, acc);
            acc = fdot2u(cw.x, tl.x, acc);
            acc = fdot2u(cw.y, tl.y, acc);
            acc = fdot2u(cw.z, tl.z, acc);
            acc = fdot2u(cw.w, tl.w, acc);
        }
        sX4[tid] = tanhf(dis[tid] * (acc + t4[tid]) + b4[0]);
    }
    __syncthreads();

    // ---- stable rank (value desc, index asc), wave-parallel ----
    if (tid < 500) {
        int i = tid / 5, seg = tid - i * 5;
        float vi = sX4[i];
        int c = 0, jb = seg * 20;
        #pragma unroll
        for (int jo = 0; jo < 20; ++jo) {
            int j = jb + jo;
            float vj = sX4[j];
            c += (vj > vi) || (vj == vi && j < i);
        }
        atomicAdd(&srank[i], c);
    }
    __syncthreads();

    // ---- gather top-30 rows into pooled[30][100] directly from frags ----
    if (wv < 7) {
        int n0 = l64 & 15, r0 = (wv << 4) + ((l64 >> 4) << 2);
        #pragma unroll
        for (int j = 0; j < 4; ++j) {
            int row = r0 + j;
            if (row < 100) {
                int rk = srank[row];
                if (rk < KTOP_C) {
                    float* pr = pooled + rk * 100;
                    pr[n0]      = f1a[j]; pr[16 + n0] = f1b[j];
                    pr[32 + n0] = f2a[j]; pr[48 + n0] = f2b[j];
                    pr[64 + n0] = f3a[j]; pr[80 + n0] = f3b[j];
                    if (n0 == 0) pr[96] = sX4[row];
                }
            }
        }
    }
    __syncthreads();

    // ---- conv5 (97 -> 16) + ReLU ----
    if (tid < 480) {
        int l = tid >> 4, co = tid & 15;
        const float* pr = pooled + l * 100;
        const float* wr = w5 + co * 97;
        float acc = b5[co];
        for (int c4 = 0; c4 < 96; c4 += 4) {
            const float4 pv = *(const float4*)&pr[c4];
            acc = fmaf(pv.x, wr[c4+0], fmaf(pv.y, wr[c4+1], fmaf(pv.z, wr[c4+2], fmaf(pv.w, wr[c4+3], acc))));
        }
        acc = fmaf(pr[96], wr[96], acc);
        s5[co * 30 + l] = fmaxf(acc, 0.f);
    }
    __syncthreads();

    // ---- maxpool(2,2) ----
    if (tid < 240) {
        int co = tid / 15, j = tid - co * 15;
        sPb[co * 15 + j] = fmaxf(s5[co * 30 + 2*j], s5[co * 30 + 2*j + 1]);
    }
    __syncthreads();

    // ---- conv6 (16 -> 32, k=5) + ReLU ----
    if (tid < 352) {
        int co = tid / 11, l = tid - co * 11;
        float acc = b6[co];
        for (int ci = 0; ci < 16; ++ci) {
            const float* wr = w6 + (co * 16 + ci) * 5;
            const float* pr = sPb + ci * 15 + l;
            acc = fmaf(wr[0], pr[0], fmaf(wr[1], pr[1], fmaf(wr[2], pr[2],
                  fmaf(wr[3], pr[3], fmaf(wr[4], pr[4], acc)))));
        }
        s6[co * 11 + l] = fmaxf(acc, 0.f);
    }
    __syncthreads();

    // ---- fc1 (352 -> 128) + ReLU ----
    {
        int j = tid & 127, part = tid >> 7;
        int ibeg = part * 88, iend = ibeg + 88;
        float acc = (part == 0) ? fb1[j] : 0.f;
        for (int i = ibeg; i < iend; ++i)
            acc = fmaf(s6[i], fw1[i * 128 + j], acc);
        sFc[part * 128 + j] = acc;
    }
    __syncthreads();
    if (tid < 128) {
        float v = sFc[tid] + sFc[128 + tid] + sFc[256 + tid] + sFc[384 + tid];
        sO1[tid] = fmaxf(v, 0.f);
    }
    __syncthreads();

    // ---- fc2 (128 -> 10) + log_softmax ----
    if (tid < 10) {
        float acc = fb2[tid];
        for (int k = 0; k < 128; ++k)
            acc = fmaf(sO1[k], fw2[k * 10 + tid], acc);
        sZ[tid] = acc;
    }
    __syncthreads();
    if (tid < 10) {
        float m = sZ[0];
        for (int c = 1; c < 10; ++c) m = fmaxf(m, sZ[c]);
        float se = 0.f;
        for (int c = 0; c < 10; ++c) se += expf(sZ[c] - m);
        out[g * 10 + tid] = sZ[tid] - m - logf(se);
    }
}

extern "C" void kernel_launch(void* const* d_in, const int* in_sizes, int n_in,
                              void* d_out, int out_size, void* d_ws, size_t ws_size,
                              hipStream_t stream) {
    const float* x   = (const float*)d_in[0];
    const int*   ei  = (const int*)d_in[1];
    const int*   src = ei;
    const int*   dst = ei + N_EDGES_C;
    const float* W1 = (const float*)d_in[3];  const float* b1 = (const float*)d_in[4];
    const float* W2 = (const float*)d_in[5];  const float* b2 = (const float*)d_in[6];
    const float* W3 = (const float*)d_in[7];  const float* b3 = (const float*)d_in[8];
    const float* W4 = (const float*)d_in[9];  const float* b4 = (const float*)d_in[10];
    const float* w5 = (const float*)d_in[11]; const float* b5 = (const float*)d_in[12];
    const float* w6 = (const float*)d_in[13]; const float* b6 = (const float*)d_in[14];
    const float* fw1 = (const float*)d_in[15]; const float* fb1 = (const float*)d_in[16];
    const float* fw2 = (const float*)d_in[17]; const float* fb2 = (const float*)d_in[18];
    float* out = (float*)d_out;

    int* gcur = (int*)d_ws;
    unsigned short* slots = (unsigned short*)((char*)d_ws + 4096);

    hipMemsetAsync(gcur, 0, 4096, stream);

    bucket_kernel<<<(N_EDGES_C + 8191) / 8192, 1024, 0, stream>>>(src, dst, gcur, slots);

    size_t smem = (size_t)SMEM_WORDS * sizeof(unsigned);  // 62,848 B -> 2 blocks/CU
    hipFuncSetAttribute((const void*)dgcnn_kernel,
                        hipFuncAttributeMaxDynamicSharedMemorySize, (int)smem);
    dgcnn_kernel<<<N_GRAPHS_C, 512, smem, stream>>>(
        x, gcur, slots, W1, b1, W2, b2, W3, b3, W4, b4,
        w5, b5, w6, b6, fw1, fb1, fw2, fb2, out);
}

// Round 11
// 112.151 us; speedup vs baseline: 3.9833x; 1.5142x over previous
//
#include <hip/hip_runtime.h>

#define N_GRAPHS_C 1000
#define NPG_C      100
#define N_EDGES_C  3200000
#define KTOP_C     30
#define CAP        4096      // per-graph edge-slot capacity (mean 3200, sigma ~57)

typedef _Float16 f16x8 __attribute__((ext_vector_type(8)));
typedef float    f32x4 __attribute__((ext_vector_type(4)));
typedef _Float16 h2_t  __attribute__((ext_vector_type(2)));

__device__ __forceinline__ float fdot2u(unsigned a, unsigned b, float c) {
#if __has_builtin(__builtin_amdgcn_fdot2)
    return __builtin_amdgcn_fdot2(__builtin_bit_cast(h2_t, a),
                                  __builtin_bit_cast(h2_t, b), c, false);
#else
    h2_t ha = __builtin_bit_cast(h2_t, a), hb = __builtin_bit_cast(h2_t, b);
    return fmaf((float)ha.x, (float)hb.x, fmaf((float)ha.y, (float)hb.y, c));
#endif
}

__device__ __forceinline__ unsigned packh2(float x, float y) {
    _Float16 hx = (_Float16)x, hy = (_Float16)y;
    return (unsigned)__builtin_bit_cast(unsigned short, hx) |
           ((unsigned)__builtin_bit_cast(unsigned short, hy) << 16);
}

__device__ __forceinline__ float f16b(unsigned v) {
    return (float)__builtin_bit_cast(_Float16, (unsigned short)v);
}

__device__ __forceinline__ float ftanh(float x) {
    float e = __expf(2.0f * x);
    return 1.0f - 2.0f * __builtin_amdgcn_rcpf(e + 1.0f);
}

__device__ __forceinline__ void split8(const float* v, f16x8& h, f16x8& l) {
    #pragma unroll
    for (int j = 0; j < 8; ++j) {
        _Float16 hh = (_Float16)v[j];
        h[j] = hh;
        l[j] = (_Float16)(v[j] - (float)hh);
    }
}

// ---------------- workspace layout (bytes) ----------------
// [0, 4096)            : gcur  int[1024]  (memset to 0)
// [4096, 4096+8.2MB)   : slots u16[1000*4096]  packed edges (d<<7 | s)

__global__ __launch_bounds__(1024)
void bucket_kernel(const int* __restrict__ src, const int* __restrict__ dst,
                   int* __restrict__ gcur, unsigned short* __restrict__ slots) {
    __shared__ int hist[N_GRAPHS_C];
    const int tid = threadIdx.x;
    const int base = blockIdx.x * 8192;
    for (int i = tid; i < N_GRAPHS_C; i += 1024) hist[i] = 0;
    __syncthreads();

    int g[8]; unsigned short pk[8]; bool v[8];
    #pragma unroll
    for (int k = 0; k < 8; ++k) {
        int e = base + tid + k * 1024;
        v[k] = false;
        if (e < N_EDGES_C) {
            int s = src[e], d = dst[e];
            if (s != d) {
                int gg = s / NPG_C;
                g[k] = gg;
                pk[k] = (unsigned short)(((d - gg * NPG_C) << 7) | (s - gg * NPG_C));
                v[k] = true;
                atomicAdd(&hist[gg], 1);
            }
        }
    }
    __syncthreads();
    for (int i = tid; i < N_GRAPHS_C; i += 1024) {
        int c = hist[i];
        hist[i] = atomicAdd(&gcur[i], c);
    }
    __syncthreads();
    #pragma unroll
    for (int k = 0; k < 8; ++k) {
        if (v[k]) {
            int pos = atomicAdd(&hist[g[k]], 1);
            if (pos < CAP) slots[g[k] * CAP + pos] = pk[k];
        }
    }
}

// ---------------- main per-graph kernel ----------------
// LDS (u32 word offsets), total 16112 words = 64,448 B -> 2 blocks/CU:
//  cntP   [0, 7616)      f16 cnt, 112 rows x 68 words (k padded to 128 f16, zeros)
//  planes [7616, 11968)  Td hi/lo: {hi,lo} x n(0..31) x 68 words; scatter u8 area = first 2600
//  xrows  [11968, 15568) f32[100][36] (stride 36 de-banks XW A-frag reads);
//                        pooled[30][100] aliases after GCN
//  dis    [15568, 15680) f32[112] (pads 0)
//  t4     [15680, 15784) f32[104]
//  t4h    [15784, 15848) t4l [15848, 15912)
//  sX4    [15912, 16012) srank [16012, 16112)
//  tail s5/sP/s6/sO1/sFc/sZ (1728 f32) aliases cntP (dead after L4 dot)
#define SMEM_WORDS 16112

extern "C" __global__ __launch_bounds__(512, 4)
void dgcnn_kernel(const float* __restrict__ x,
                  const int* __restrict__ gcur, const unsigned short* __restrict__ slots,
                  const float* __restrict__ W1, const float* __restrict__ b1,
                  const float* __restrict__ W2, const float* __restrict__ b2,
                  const float* __restrict__ W3, const float* __restrict__ b3,
                  const float* __restrict__ W4, const float* __restrict__ b4,
                  const float* __restrict__ w5, const float* __restrict__ b5,
                  const float* __restrict__ w6, const float* __restrict__ b6,
                  const float* __restrict__ fw1, const float* __restrict__ fb1,
                  const float* __restrict__ fw2, const float* __restrict__ fb2,
                  float* __restrict__ out)
{
    extern __shared__ unsigned smu[];
    unsigned* cntP   = smu;                    // 7616
    unsigned* planes = smu + 7616;             // 4352 (scatter area = first 2600)
    float* xrows  = (float*)(smu + 11968);     // 3600, stride 36
    float* pooled = (float*)(smu + 11968);     // [30][100] aliases xrows (dead)
    float* dis = (float*)(smu + 15568);        // 112
    float* t4  = (float*)(smu + 15680);        // 104
    unsigned* t4h = smu + 15784;               // 64
    unsigned* t4l = smu + 15848;               // 64
    float* sX4 = (float*)(smu + 15912);        // 100
    int*   srank = (int*)(smu + 16012);        // 100
    float* s5  = (float*)smu;                  // tail aliases cntP
    float* sPb = s5 + 480;
    float* s6  = s5 + 720;
    float* sO1 = s5 + 1072;
    float* sFc = s5 + 1200;
    float* sZ  = s5 + 1712;

    const int tid = threadIdx.x;
    const int g   = blockIdx.x;
    const int l64 = tid & 63;
    const int wv  = tid >> 6;                  // 0..7

    const float* xg = x + (size_t)g * NPG_C * 128;

    // ---- P0: zero cntP + planes (incl. scatter area & pads); dis pads ----
    for (int idx = tid; idx < 11968; idx += 512) smu[idx] = 0u;
    if (tid < 12) dis[100 + tid] = 0.f;
    __syncthreads();

    // ---- P1: scatter u8 counts into planes-region (u8[100][104]) ----
    {
        int ec = gcur[g]; if (ec > CAP) ec = CAP;
        for (int k = tid; k < ec; k += 512) {
            unsigned e = slots[g * CAP + k];
            unsigned idx = (e >> 7) * 104 + (e & 127);
            atomicAdd(&planes[idx >> 2], 1u << ((idx & 3) * 8));
        }
    }
    __syncthreads();

    // ---- P2: dis = rsqrt(rowsum+1) ----
    if (tid < 100) {
        const unsigned* rw = planes + tid * 26;
        unsigned s = 0;
        #pragma unroll
        for (int k = 0; k < 26; ++k) {
            unsigned v = rw[k];
            s += (v & 0xffu) + ((v >> 8) & 0xffu) + ((v >> 16) & 0xffu) + (v >> 24);
        }
        dis[tid] = rsqrtf((float)s + 1.0f);
    }
    __syncthreads();

    // ---- P3: expand u8 counts -> f16 pairs in cntP ----
    #pragma unroll
    for (int k = 0; k < 6; ++k) {
        int w = tid + k * 512;
        if (w < 2600) {
            unsigned v = planes[w];
            int i = w / 26, c = w - i * 26;
            int d = i * 68 + c * 2;
            cntP[d]     = packh2((float)(v & 255u), (float)((v >> 8) & 255u));
            cntP[d + 1] = packh2((float)((v >> 16) & 255u), (float)(v >> 24));
        }
    }
    __syncthreads();

    // ---- C-frag -> Td planes: v = c*dis, pack f16 hi/lo pairs, b64 store ----
    auto packStore = [&](f32x4 c, int n, int r0, float4 dv) {
        float v0 = c[0]*dv.x, v1 = c[1]*dv.y, v2 = c[2]*dv.z, v3 = c[3]*dv.w;
        _Float16 h0=(_Float16)v0, h1=(_Float16)v1, h2=(_Float16)v2, h3=(_Float16)v3;
        uint2 wh, wl;
        wh.x = (unsigned)__builtin_bit_cast(unsigned short,h0) |
               ((unsigned)__builtin_bit_cast(unsigned short,h1) << 16);
        wh.y = (unsigned)__builtin_bit_cast(unsigned short,h2) |
               ((unsigned)__builtin_bit_cast(unsigned short,h3) << 16);
        wl.x = packh2(v0-(float)h0, v1-(float)h1);
        wl.y = packh2(v2-(float)h2, v3-(float)h3);
        *(uint2*)&planes[n*68 + (r0>>1)] = wh;
        *(uint2*)&planes[2176 + n*68 + (r0>>1)] = wl;
    };

    // ---- P4: zero plane pad words 56..67 per n-row; L1 = X @ W1 via MFMA ----
    for (int idx = tid; idx < 768; idx += 512) {
        int rw = idx / 12, wd = idx - rw * 12;
        planes[rw * 68 + 56 + wd] = 0u;
    }
    if (wv < 7) {
        f32x4 c0 = {0.f,0.f,0.f,0.f}, c1 = {0.f,0.f,0.f,0.f};
        const int arow = (wv << 4) + (l64 & 15);   // 0..111
        const int kq   = (l64 >> 4) << 3;          // 0,8,16,24
        const int bn   = l64 & 15;
        const bool aok = arow < 100;
        #pragma unroll
        for (int kc = 0; kc < 4; ++kc) {
            const int kb = (kc << 5) + kq;
            float av[8];
            if (aok) {
                float4 xa = *(const float4*)&xg[arow*128 + kb];
                float4 xb = *(const float4*)&xg[arow*128 + kb + 4];
                av[0]=xa.x; av[1]=xa.y; av[2]=xa.z; av[3]=xa.w;
                av[4]=xb.x; av[5]=xb.y; av[6]=xb.z; av[7]=xb.w;
            } else {
                #pragma unroll
                for (int j = 0; j < 8; ++j) av[j] = 0.f;
            }
            f16x8 ah, al; split8(av, ah, al);
            float b0[8], b1[8];
            #pragma unroll
            for (int i = 0; i < 8; ++i) {
                b0[i] = W1[(kb+i)*32 + bn];
                b1[i] = W1[(kb+i)*32 + 16 + bn];
            }
            f16x8 b0h,b0l,b1h,b1l; split8(b0,b0h,b0l); split8(b1,b1h,b1l);
            c0 = __builtin_amdgcn_mfma_f32_16x16x32_f16(ah, b0h, c0, 0, 0, 0);
            c0 = __builtin_amdgcn_mfma_f32_16x16x32_f16(al, b0h, c0, 0, 0, 0);
            c0 = __builtin_amdgcn_mfma_f32_16x16x32_f16(ah, b0l, c0, 0, 0, 0);
            c1 = __builtin_amdgcn_mfma_f32_16x16x32_f16(ah, b1h, c1, 0, 0, 0);
            c1 = __builtin_amdgcn_mfma_f32_16x16x32_f16(al, b1h, c1, 0, 0, 0);
            c1 = __builtin_amdgcn_mfma_f32_16x16x32_f16(ah, b1l, c1, 0, 0, 0);
        }
        const int r0 = (wv << 4) + ((l64 >> 4) << 2);
        float4 dv = *(const float4*)&dis[r0];
        packStore(c0, bn,      r0, dv);
        packStore(c1, bn + 16, r0, dv);
    }
    __syncthreads();

    // ---- AGG via MFMA (unchanged layout; xrows stride 36) ----
    auto AGG = [&](f32x4& fa, f32x4& fb, const float* Bp, bool wx) {
        if (wv < 7) {
            f32x4 a0 = {0.f,0.f,0.f,0.f}, a1 = {0.f,0.f,0.f,0.f};
            const unsigned* ab = cntP + ((wv << 4) + (l64 & 15)) * 68 + ((l64 >> 4) << 2);
            const unsigned* bb = planes + (l64 & 15) * 68 + ((l64 >> 4) << 2);
            #pragma unroll
            for (int p = 0; p < 2; ++p) {
                const unsigned* bp = bb + p * 2176;
                #pragma unroll
                for (int ks = 0; ks < 4; ++ks) {
                    f16x8 av = __builtin_bit_cast(f16x8, *(const uint4*)(ab + ks*16));
                    f16x8 b0 = __builtin_bit_cast(f16x8, *(const uint4*)(bp + ks*16));
                    f16x8 b1 = __builtin_bit_cast(f16x8, *(const uint4*)(bp + 16*68 + ks*16));
                    a0 = __builtin_amdgcn_mfma_f32_16x16x32_f16(av, b0, a0, 0, 0, 0);
                    a1 = __builtin_amdgcn_mfma_f32_16x16x32_f16(av, b1, a1, 0, 0, 0);
                }
            }
            int n0 = l64 & 15, r0 = (wv << 4) + ((l64 >> 4) << 2);
            uint2 sh0 = *(const uint2*)(planes + n0 * 68 + (r0 >> 1));
            uint2 sl0 = *(const uint2*)(planes + 2176 + n0 * 68 + (r0 >> 1));
            uint2 sh1 = *(const uint2*)(planes + (16 + n0) * 68 + (r0 >> 1));
            uint2 sl1 = *(const uint2*)(planes + 2176 + (16 + n0) * 68 + (r0 >> 1));
            float4 dv = *(const float4*)&dis[r0];
            float bi0 = Bp[n0], bi1 = Bp[16 + n0];
            #pragma unroll
            for (int j = 0; j < 4; ++j) {
                unsigned sft = (unsigned)((j & 1) * 16);
                float sc0 = f16b(((j < 2) ? sh0.x : sh0.y) >> sft) +
                            f16b(((j < 2) ? sl0.x : sl0.y) >> sft);
                float sc1 = f16b(((j < 2) ? sh1.x : sh1.y) >> sft) +
                            f16b(((j < 2) ? sl1.x : sl1.y) >> sft);
                float d_ = (j == 0) ? dv.x : (j == 1) ? dv.y : (j == 2) ? dv.z : dv.w;
                float v0 = ftanh(d_ * (a0[j] + sc0) + bi0);
                float v1 = ftanh(d_ * (a1[j] + sc1) + bi1);
                fa[j] = v0; fb[j] = v1;
                if (wx) {
                    int row = r0 + j;
                    if (row < 100) { xrows[row*36 + n0] = v0; xrows[row*36 + 16 + n0] = v1; }
                }
            }
        }
    };

    // ---- XW via MFMA: T = xrows @ W (K=32), scale by dis, pack to planes ----
    auto XWm = [&](const float* W) {
        if (wv < 7) {
            f32x4 c0 = {0.f,0.f,0.f,0.f}, c1 = {0.f,0.f,0.f,0.f};
            const int arow = (wv << 4) + (l64 & 15);
            const int kq   = (l64 >> 4) << 3;
            const int bn   = l64 & 15;
            float av[8];
            if (arow < 100) {
                float4 xa = *(const float4*)&xrows[arow*36 + kq];
                float4 xb = *(const float4*)&xrows[arow*36 + kq + 4];
                av[0]=xa.x; av[1]=xa.y; av[2]=xa.z; av[3]=xa.w;
                av[4]=xb.x; av[5]=xb.y; av[6]=xb.z; av[7]=xb.w;
            } else {
                #pragma unroll
                for (int j = 0; j < 8; ++j) av[j] = 0.f;
            }
            f16x8 ah, al; split8(av, ah, al);
            float b0[8], b1[8];
            #pragma unroll
            for (int i = 0; i < 8; ++i) {
                b0[i] = W[(kq+i)*32 + bn];
                b1[i] = W[(kq+i)*32 + 16 + bn];
            }
            f16x8 b0h,b0l,b1h,b1l; split8(b0,b0h,b0l); split8(b1,b1h,b1l);
            c0 = __builtin_amdgcn_mfma_f32_16x16x32_f16(ah, b0h, c0, 0, 0, 0);
            c0 = __builtin_amdgcn_mfma_f32_16x16x32_f16(al, b0h, c0, 0, 0, 0);
            c0 = __builtin_amdgcn_mfma_f32_16x16x32_f16(ah, b0l, c0, 0, 0, 0);
            c1 = __builtin_amdgcn_mfma_f32_16x16x32_f16(ah, b1h, c1, 0, 0, 0);
            c1 = __builtin_amdgcn_mfma_f32_16x16x32_f16(al, b1h, c1, 0, 0, 0);
            c1 = __builtin_amdgcn_mfma_f32_16x16x32_f16(ah, b1l, c1, 0, 0, 0);
            const int r0 = (wv << 4) + ((l64 >> 4) << 2);
            float4 dv = *(const float4*)&dis[r0];
            packStore(c0, bn,      r0, dv);
            packStore(c1, bn + 16, r0, dv);
        }
    };

    f32x4 f1a, f1b, f2a, f2b, f3a, f3b;

    AGG(f1a, f1b, b1, true);   __syncthreads();
    XWm(W2);                   __syncthreads();
    AGG(f2a, f2b, b2, true);   __syncthreads();
    XWm(W3);                   __syncthreads();
    AGG(f3a, f3b, b3, false);

    // ---- L4 (32->1) from x3 frags via 16-lane shfl reduce ----
    if (wv < 7) {
        float w4a = W4[l64 & 15], w4b = W4[16 + (l64 & 15)];
        int r0 = (wv << 4) + ((l64 >> 4) << 2);
        #pragma unroll
        for (int j = 0; j < 4; ++j) {
            float v = f3a[j] * w4a + f3b[j] * w4b;
            v += __shfl_xor(v, 1, 16); v += __shfl_xor(v, 2, 16);
            v += __shfl_xor(v, 4, 16); v += __shfl_xor(v, 8, 16);
            int row = r0 + j;
            if ((l64 & 15) == 0 && row < 100) t4[row] = v * dis[row];
        }
    }
    if (tid < 100) srank[tid] = 0;
    __syncthreads();

    // ---- pack t4 hi/lo (64 words, pads zero) ----
    if (tid < 64) {
        float a = (2*tid < 100) ? t4[2*tid] : 0.f;
        float b = (2*tid+1 < 100) ? t4[2*tid+1] : 0.f;
        _Float16 ah = (_Float16)a, bh = (_Float16)b;
        t4h[tid] = (unsigned)__builtin_bit_cast(unsigned short, ah) |
                   ((unsigned)__builtin_bit_cast(unsigned short, bh) << 16);
        t4l[tid] = packh2(a - (float)ah, b - (float)bh);
    }
    __syncthreads();

    // ---- L4 dot (dot2 over cntP rows) + exact tanh (sort keys) ----
    if (tid < 100) {
        float acc = 0.f;
        const unsigned* cr = cntP + tid * 68;
        for (int kc = 0; kc < 16; ++kc) {
            uint4 cw = *(const uint4*)&cr[kc*4];
            uint4 th = *(const uint4*)&t4h[kc*4];
            uint4 tl = *(const uint4*)&t4l[kc*4];
            acc = fdot2u(cw.x, th.x, acc);
            acc = fdot2u(cw.y, th.y, acc);
            acc = fdot2u(cw.z, th.z, acc);
            acc = fdot2u(cw.w, th.w, acc);
            acc = fdot2u(cw.x, tl.x, acc);
            acc = fdot2u(cw.y, tl.y, acc);
            acc = fdot2u(cw.z, tl.z, acc);
            acc = fdot2u(cw.w, tl.w, acc);
        }
        sX4[tid] = tanhf(dis[tid] * (acc + t4[tid]) + b4[0]);
    }
    __syncthreads();

    // ---- stable rank (value desc, index asc), wave-parallel ----
    if (tid < 500) {
        int i = tid / 5, seg = tid - i * 5;
        float vi = sX4[i];
        int c = 0, jb = seg * 20;
        #pragma unroll
        for (int jo = 0; jo < 20; ++jo) {
            int j = jb + jo;
            float vj = sX4[j];
            c += (vj > vi) || (vj == vi && j < i);
        }
        atomicAdd(&srank[i], c);
    }
    __syncthreads();

    // ---- gather top-30 rows into pooled[30][100] directly from frags ----
    if (wv < 7) {
        int n0 = l64 & 15, r0 = (wv << 4) + ((l64 >> 4) << 2);
        #pragma unroll
        for (int j = 0; j < 4; ++j) {
            int row = r0 + j;
            if (row < 100) {
                int rk = srank[row];
                if (rk < KTOP_C) {
                    float* pr = pooled + rk * 100;
                    pr[n0]      = f1a[j]; pr[16 + n0] = f1b[j];
                    pr[32 + n0] = f2a[j]; pr[48 + n0] = f2b[j];
                    pr[64 + n0] = f3a[j]; pr[80 + n0] = f3b[j];
                    if (n0 == 0) pr[96] = sX4[row];
                }
            }
        }
    }
    __syncthreads();

    // ---- conv5 (97 -> 16) + ReLU ----
    if (tid < 480) {
        int l = tid >> 4, co = tid & 15;
        const float* pr = pooled + l * 100;
        const float* wr = w5 + co * 97;
        float acc = b5[co];
        for (int c4 = 0; c4 < 96; c4 += 4) {
            const float4 pv = *(const float4*)&pr[c4];
            acc = fmaf(pv.x, wr[c4+0], fmaf(pv.y, wr[c4+1], fmaf(pv.z, wr[c4+2], fmaf(pv.w, wr[c4+3], acc))));
        }
        acc = fmaf(pr[96], wr[96], acc);
        s5[co * 30 + l] = fmaxf(acc, 0.f);
    }
    __syncthreads();

    // ---- maxpool(2,2) ----
    if (tid < 240) {
        int co = tid / 15, j = tid - co * 15;
        sPb[co * 15 + j] = fmaxf(s5[co * 30 + 2*j], s5[co * 30 + 2*j + 1]);
    }
    __syncthreads();

    // ---- conv6 (16 -> 32, k=5) + ReLU ----
    if (tid < 352) {
        int co = tid / 11, l = tid - co * 11;
        float acc = b6[co];
        for (int ci = 0; ci < 16; ++ci) {
            const float* wr = w6 + (co * 16 + ci) * 5;
            const float* pr = sPb + ci * 15 + l;
            acc = fmaf(wr[0], pr[0], fmaf(wr[1], pr[1], fmaf(wr[2], pr[2],
                  fmaf(wr[3], pr[3], fmaf(wr[4], pr[4], acc)))));
        }
        s6[co * 11 + l] = fmaxf(acc, 0.f);
    }
    __syncthreads();

    // ---- fc1 (352 -> 128) + ReLU ----
    {
        int j = tid & 127, part = tid >> 7;
        int ibeg = part * 88, iend = ibeg + 88;
        float acc = (part == 0) ? fb1[j] : 0.f;
        for (int i = ibeg; i < iend; ++i)
            acc = fmaf(s6[i], fw1[i * 128 + j], acc);
        sFc[part * 128 + j] = acc;
    }
    __syncthreads();
    if (tid < 128) {
        float v = sFc[tid] + sFc[128 + tid] + sFc[256 + tid] + sFc[384 + tid];
        sO1[tid] = fmaxf(v, 0.f);
    }
    __syncthreads();

    // ---- fc2 (128 -> 10) + log_softmax ----
    if (tid < 10) {
        float acc = fb2[tid];
        for (int k = 0; k < 128; ++k)
            acc = fmaf(sO1[k], fw2[k * 10 + tid], acc);
        sZ[tid] = acc;
    }
    __syncthreads();
    if (tid < 10) {
        float m = sZ[0];
        for (int c = 1; c < 10; ++c) m = fmaxf(m, sZ[c]);
        float se = 0.f;
        for (int c = 0; c < 10; ++c) se += expf(sZ[c] - m);
        out[g * 10 + tid] = sZ[tid] - m - logf(se);
    }
}

extern "C" void kernel_launch(void* const* d_in, const int* in_sizes, int n_in,
                              void* d_out, int out_size, void* d_ws, size_t ws_size,
                              hipStream_t stream) {
    const float* x   = (const float*)d_in[0];
    const int*   ei  = (const int*)d_in[1];
    const int*   src = ei;
    const int*   dst = ei + N_EDGES_C;
    const float* W1 = (const float*)d_in[3];  const float* b1 = (const float*)d_in[4];
    const float* W2 = (const float*)d_in[5];  const float* b2 = (const float*)d_in[6];
    const float* W3 = (const float*)d_in[7];  const float* b3 = (const float*)d_in[8];
    const float* W4 = (const float*)d_in[9];  const float* b4 = (const float*)d_in[10];
    const float* w5 = (const float*)d_in[11]; const float* b5 = (const float*)d_in[12];
    const float* w6 = (const float*)d_in[13]; const float* b6 = (const float*)d_in[14];
    const float* fw1 = (const float*)d_in[15]; const float* fb1 = (const float*)d_in[16];
    const float* fw2 = (const float*)d_in[17]; const float* fb2 = (const float*)d_in[18];
    float* out = (float*)d_out;

    int* gcur = (int*)d_ws;
    unsigned short* slots = (unsigned short*)((char*)d_ws + 4096);

    hipMemsetAsync(gcur, 0, 4096, stream);

    bucket_kernel<<<(N_EDGES_C + 8191) / 8192, 1024, 0, stream>>>(src, dst, gcur, slots);

    size_t smem = (size_t)SMEM_WORDS * sizeof(unsigned);  // 64,448 B -> 2 blocks/CU
    hipFuncSetAttribute((const void*)dgcnn_kernel,
                        hipFuncAttributeMaxDynamicSharedMemorySize, (int)smem);
    dgcnn_kernel<<<N_GRAPHS_C, 512, smem, stream>>>(
        x, gcur, slots, W1, b1, W2, b2, W3, b3, W4, b4,
        w5, b5, w6, b6, fw1, fb1, fw2, fb2, out);
}

// Round 14
// 110.079 us; speedup vs baseline: 4.0582x; 1.0188x over previous
//
#include <hip/hip_runtime.h>

#define N_GRAPHS_C 1000
#define NPG_C      100
#define N_EDGES_C  3200000
#define KTOP_C     30
#define CAP        4096      // per-graph edge-slot capacity (mean 3200, sigma ~57)

typedef _Float16 f16x8 __attribute__((ext_vector_type(8)));
typedef float    f32x4 __attribute__((ext_vector_type(4)));

__device__ __forceinline__ unsigned packh2(float x, float y) {
    _Float16 hx = (_Float16)x, hy = (_Float16)y;
    return (unsigned)__builtin_bit_cast(unsigned short, hx) |
           ((unsigned)__builtin_bit_cast(unsigned short, hy) << 16);
}

__device__ __forceinline__ float f16b(unsigned v) {
    return (float)__builtin_bit_cast(_Float16, (unsigned short)v);
}

__device__ __forceinline__ float ftanh(float x) {
    float e = __expf(2.0f * x);
    return 1.0f - 2.0f * __builtin_amdgcn_rcpf(e + 1.0f);
}

__device__ __forceinline__ void split8(const float* v, f16x8& h, f16x8& l) {
    #pragma unroll
    for (int j = 0; j < 8; ++j) {
        _Float16 hh = (_Float16)v[j];
        h[j] = hh;
        l[j] = (_Float16)(v[j] - (float)hh);
    }
}

// ---------------- workspace layout (bytes) ----------------
// [0, 4096)                 : gcur  int[1024]  (memset to 0)
// [4096, 8196096)           : slots u16[1000*4096]  packed edges (d<<7 | s)
// [8196096, +6144 words)    : wp — precomputed f16 hi/lo planes of W1/W2/W3
//   wp[0..2048)   W1 hi  [32 cols][64 kpairs]
//   wp[2048..4096) W1 lo
//   wp[4096..4608) W2 hi  [32][16]
//   wp[4608..5120) W2 lo
//   wp[5120..5632) W3 hi
//   wp[5632..6144) W3 lo

__global__ __launch_bounds__(1024)
void bucket_kernel(const int* __restrict__ src, const int* __restrict__ dst,
                   int* __restrict__ gcur, unsigned short* __restrict__ slots) {
    __shared__ int hist[N_GRAPHS_C];
    const int tid = threadIdx.x;
    const int base = blockIdx.x * 8192;
    for (int i = tid; i < N_GRAPHS_C; i += 1024) hist[i] = 0;
    __syncthreads();

    int g[8]; unsigned short pk[8]; bool v[8];
    #pragma unroll
    for (int k = 0; k < 8; ++k) {
        int e = base + tid + k * 1024;
        v[k] = false;
        if (e < N_EDGES_C) {
            int s = src[e], d = dst[e];
            if (s != d) {
                int gg = s / NPG_C;
                g[k] = gg;
                pk[k] = (unsigned short)(((d - gg * NPG_C) << 7) | (s - gg * NPG_C));
                v[k] = true;
                atomicAdd(&hist[gg], 1);
            }
        }
    }
    __syncthreads();
    for (int i = tid; i < N_GRAPHS_C; i += 1024) {
        int c = hist[i];
        hist[i] = atomicAdd(&gcur[i], c);
    }
    __syncthreads();
    #pragma unroll
    for (int k = 0; k < 8; ++k) {
        if (v[k]) {
            int pos = atomicAdd(&hist[g[k]], 1);
            if (pos < CAP) slots[g[k] * CAP + pos] = pk[k];
        }
    }
}

__global__ __launch_bounds__(512)
void wprep_kernel(const float* __restrict__ W1, const float* __restrict__ W2,
                  const float* __restrict__ W3, unsigned* __restrict__ wp) {
    const int t = threadIdx.x;
    for (int w = t; w < 2048; w += 512) {         // W1: 32 cols x 64 kpairs
        int n = w >> 6, kp = w & 63, k = kp * 2;
        float a = W1[k*32 + n], b = W1[(k+1)*32 + n];
        _Float16 ah = (_Float16)a, bh = (_Float16)b;
        wp[w]        = (unsigned)__builtin_bit_cast(unsigned short, ah) |
                       ((unsigned)__builtin_bit_cast(unsigned short, bh) << 16);
        wp[2048 + w] = packh2(a - (float)ah, b - (float)bh);
    }
    for (int w = t; w < 512; w += 512) {          // W2: 32 cols x 16 kpairs
        int n = w >> 4, kp = w & 15, k = kp * 2;
        float a = W2[k*32 + n], b = W2[(k+1)*32 + n];
        _Float16 ah = (_Float16)a, bh = (_Float16)b;
        wp[4096 + w] = (unsigned)__builtin_bit_cast(unsigned short, ah) |
                       ((unsigned)__builtin_bit_cast(unsigned short, bh) << 16);
        wp[4608 + w] = packh2(a - (float)ah, b - (float)bh);
    }
    for (int w = t; w < 512; w += 512) {          // W3
        int n = w >> 4, kp = w & 15, k = kp * 2;
        float a = W3[k*32 + n], b = W3[(k+1)*32 + n];
        _Float16 ah = (_Float16)a, bh = (_Float16)b;
        wp[5120 + w] = (unsigned)__builtin_bit_cast(unsigned short, ah) |
                       ((unsigned)__builtin_bit_cast(unsigned short, bh) << 16);
        wp[5632 + w] = packh2(a - (float)ah, b - (float)bh);
    }
}

// ---------------- main per-graph kernel ----------------
// LDS (u32 word offsets), total 16112 words = 64,448 B -> 2 blocks/CU:
//  cntP   [0, 7616)      f16 cnt, 112 rows x 68 words (k padded to 128 f16, zeros)
//  planes [7616, 11968)  Td hi/lo planes; scatter u8 area = first 2600 words
//  xrows  [11968, 15568) f32[100][36]; pooled[30][100] aliases after GCN
//  dis    [15568, 15680) f32[112] (pads 0)
//  t4     [15680, 15784) f32[104]
//  t4h    [15784, 15848) t4l [15848, 15912)
//  sX4    [15912, 16012) srank [16012, 16112)  (srank doubles as rowsum early)
//  tail: bufs s5..sZ in [0,1728); staged w5/b5/w6/b6 in [1728,5888); fw2/fb2 in planes
#define SMEM_WORDS 16112

extern "C" __global__ __launch_bounds__(512, 4)
void dgcnn_kernel(const float* __restrict__ x,
                  const int* __restrict__ gcur, const unsigned short* __restrict__ slots,
                  const unsigned* __restrict__ wp,
                  const float* __restrict__ b1, const float* __restrict__ b2,
                  const float* __restrict__ b3,
                  const float* __restrict__ W4, const float* __restrict__ b4,
                  const float* __restrict__ w5, const float* __restrict__ b5,
                  const float* __restrict__ w6, const float* __restrict__ b6,
                  const float* __restrict__ fw1, const float* __restrict__ fb1,
                  const float* __restrict__ fw2, const float* __restrict__ fb2,
                  float* __restrict__ out)
{
    extern __shared__ unsigned smu[];
    unsigned* cntP   = smu;                    // 7616
    unsigned* planes = smu + 7616;             // 4352 (scatter area = first 2600)
    float* xrows  = (float*)(smu + 11968);     // 3600, stride 36
    float* pooled = (float*)(smu + 11968);     // [30][100] aliases xrows (dead)
    float* dis = (float*)(smu + 15568);        // 112
    float* t4  = (float*)(smu + 15680);        // 104
    unsigned* t4h = smu + 15784;               // 64
    unsigned* t4l = smu + 15848;               // 64
    float* sX4 = (float*)(smu + 15912);        // 100
    int*   srank = (int*)(smu + 16012);        // 100 (rowsum early, rank late)
    float* s5  = (float*)smu;                  // tail bufs alias cntP
    float* sPb = s5 + 480;
    float* s6  = s5 + 720;
    float* sO1 = s5 + 1072;
    float* sFc = s5 + 1200;
    float* sZ  = s5 + 1712;
    float* w5s = (float*)(smu + 1728);         // 1552
    float* b5s = (float*)(smu + 3280);         // 16
    float* w6s = (float*)(smu + 3296);         // 2560
    float* b6s = (float*)(smu + 5856);         // 32
    float* fw2s = (float*)(smu + 7616);        // 1280 (planes region, dead)
    float* fb2s = (float*)(smu + 8896);        // 10

    const int tid = threadIdx.x;
    const int g   = blockIdx.x;
    const int l64 = tid & 63;
    const int wv  = tid >> 6;                  // 0..7

    const float* xg = x + (size_t)g * NPG_C * 128;
    const unsigned* w1h = wp;
    const unsigned* w1l = wp + 2048;

    // ---- P0: zero cntP + planes; dis pads; rowsum accumulator ----
    for (int idx = tid; idx < 11968; idx += 512) smu[idx] = 0u;
    if (tid < 12) dis[100 + tid] = 0.f;
    if (tid < 100) srank[tid] = 0;
    __syncthreads();

    // ---- P1: scatter u8 counts into planes-region (u8[100][104]) ----
    {
        int ec = gcur[g]; if (ec > CAP) ec = CAP;
        for (int k = tid; k < ec; k += 512) {
            unsigned e = slots[g * CAP + k];
            unsigned idx = (e >> 7) * 104 + (e & 127);
            atomicAdd(&planes[idx >> 2], 1u << ((idx & 3) * 8));
        }
    }
    __syncthreads();

    // ---- P2: wave-parallel rowsums (400 threads, LDS atomics) ----
    if (tid < 400) {
        int row = tid >> 2, part = tid & 3;
        int wb = part * 7, we = (part == 3) ? 26 : wb + 7;
        const unsigned* rw = planes + row * 26;
        unsigned s = 0;
        for (int k = wb; k < we; ++k) {
            unsigned v = rw[k];
            s += (v & 0xffu) + ((v >> 8) & 0xffu) + ((v >> 16) & 0xffu) + (v >> 24);
        }
        atomicAdd(&srank[row], (int)s);
    }
    __syncthreads();

    // ---- P3: expand u8 -> f16 pairs in cntP; dis = rsqrt(sum+1) ----
    #pragma unroll
    for (int k = 0; k < 6; ++k) {
        int w = tid + k * 512;
        if (w < 2600) {
            unsigned v = planes[w];
            int i = w / 26, c = w - i * 26;
            int d = i * 68 + c * 2;
            cntP[d]     = packh2((float)(v & 255u), (float)((v >> 8) & 255u));
            cntP[d + 1] = packh2((float)((v >> 16) & 255u), (float)(v >> 24));
        }
    }
    if (tid < 100) dis[tid] = rsqrtf((float)srank[tid] + 1.0f);
    __syncthreads();

    // ---- C-frag -> Td planes: v = c*dis, pack f16 hi/lo pairs, b64 store ----
    auto packStore = [&](f32x4 c, int n, int r0, float4 dv) {
        float v0 = c[0]*dv.x, v1 = c[1]*dv.y, v2 = c[2]*dv.z, v3 = c[3]*dv.w;
        _Float16 h0=(_Float16)v0, h1=(_Float16)v1, h2=(_Float16)v2, h3=(_Float16)v3;
        uint2 wh, wl;
        wh.x = (unsigned)__builtin_bit_cast(unsigned short,h0) |
               ((unsigned)__builtin_bit_cast(unsigned short,h1) << 16);
        wh.y = (unsigned)__builtin_bit_cast(unsigned short,h2) |
               ((unsigned)__builtin_bit_cast(unsigned short,h3) << 16);
        wl.x = packh2(v0-(float)h0, v1-(float)h1);
        wl.y = packh2(v2-(float)h2, v3-(float)h3);
        *(uint2*)&planes[n*68 + (r0>>1)] = wh;
        *(uint2*)&planes[2176 + n*68 + (r0>>1)] = wl;
    };

    // ---- P4: zero plane k-pad words; L1 = X @ W1 via MFMA (B from wp) ----
    for (int idx = tid; idx < 768; idx += 512) {
        int rw = idx / 12, wd = idx - rw * 12;
        planes[rw * 68 + 56 + wd] = 0u;
    }
    if (wv < 7) {
        f32x4 c0 = {0.f,0.f,0.f,0.f}, c1 = {0.f,0.f,0.f,0.f};
        const int arow = (wv << 4) + (l64 & 15);   // 0..111
        const int kq   = (l64 >> 4) << 3;          // 0,8,16,24
        const int bn   = l64 & 15;
        const bool aok = arow < 100;
        #pragma unroll
        for (int kc = 0; kc < 4; ++kc) {
            const int kb = (kc << 5) + kq;
            f16x8 ah, al;
            if (aok) {
                float av[8];
                float4 xa = *(const float4*)&xg[arow*128 + kb];
                float4 xb = *(const float4*)&xg[arow*128 + kb + 4];
                av[0]=xa.x; av[1]=xa.y; av[2]=xa.z; av[3]=xa.w;
                av[4]=xb.x; av[5]=xb.y; av[6]=xb.z; av[7]=xb.w;
                split8(av, ah, al);
            } else {
                #pragma unroll
                for (int j = 0; j < 8; ++j) { ah[j] = (_Float16)0.f; al[j] = (_Float16)0.f; }
            }
            f16x8 b0h = __builtin_bit_cast(f16x8, *(const uint4*)(w1h + bn*64 + (kb>>1)));
            f16x8 b0l = __builtin_bit_cast(f16x8, *(const uint4*)(w1l + bn*64 + (kb>>1)));
            f16x8 b1h = __builtin_bit_cast(f16x8, *(const uint4*)(w1h + (bn+16)*64 + (kb>>1)));
            f16x8 b1l = __builtin_bit_cast(f16x8, *(const uint4*)(w1l + (bn+16)*64 + (kb>>1)));
            c0 = __builtin_amdgcn_mfma_f32_16x16x32_f16(ah, b0h, c0, 0, 0, 0);
            c0 = __builtin_amdgcn_mfma_f32_16x16x32_f16(al, b0h, c0, 0, 0, 0);
            c0 = __builtin_amdgcn_mfma_f32_16x16x32_f16(ah, b0l, c0, 0, 0, 0);
            c1 = __builtin_amdgcn_mfma_f32_16x16x32_f16(ah, b1h, c1, 0, 0, 0);
            c1 = __builtin_amdgcn_mfma_f32_16x16x32_f16(al, b1h, c1, 0, 0, 0);
            c1 = __builtin_amdgcn_mfma_f32_16x16x32_f16(ah, b1l, c1, 0, 0, 0);
        }
        const int r0 = (wv << 4) + ((l64 >> 4) << 2);
        float4 dv = *(const float4*)&dis[r0];
        packStore(c0, bn,      r0, dv);
        packStore(c1, bn + 16, r0, dv);
    }
    __syncthreads();

    // ---- AGG via MFMA ----
    auto AGG = [&](f32x4& fa, f32x4& fb, const float* Bp, bool wx) {
        if (wv < 7) {
            f32x4 a0 = {0.f,0.f,0.f,0.f}, a1 = {0.f,0.f,0.f,0.f};
            const unsigned* ab = cntP + ((wv << 4) + (l64 & 15)) * 68 + ((l64 >> 4) << 2);
            const unsigned* bb = planes + (l64 & 15) * 68 + ((l64 >> 4) << 2);
            #pragma unroll
            for (int p = 0; p < 2; ++p) {
                const unsigned* bp = bb + p * 2176;
                #pragma unroll
                for (int ks = 0; ks < 4; ++ks) {
                    f16x8 av = __builtin_bit_cast(f16x8, *(const uint4*)(ab + ks*16));
                    f16x8 b0 = __builtin_bit_cast(f16x8, *(const uint4*)(bp + ks*16));
                    f16x8 b1 = __builtin_bit_cast(f16x8, *(const uint4*)(bp + 16*68 + ks*16));
                    a0 = __builtin_amdgcn_mfma_f32_16x16x32_f16(av, b0, a0, 0, 0, 0);
                    a1 = __builtin_amdgcn_mfma_f32_16x16x32_f16(av, b1, a1, 0, 0, 0);
                }
            }
            int n0 = l64 & 15, r0 = (wv << 4) + ((l64 >> 4) << 2);
            uint2 sh0 = *(const uint2*)(planes + n0 * 68 + (r0 >> 1));
            uint2 sl0 = *(const uint2*)(planes + 2176 + n0 * 68 + (r0 >> 1));
            uint2 sh1 = *(const uint2*)(planes + (16 + n0) * 68 + (r0 >> 1));
            uint2 sl1 = *(const uint2*)(planes + 2176 + (16 + n0) * 68 + (r0 >> 1));
            float4 dv = *(const float4*)&dis[r0];
            float bi0 = Bp[n0], bi1 = Bp[16 + n0];
            #pragma unroll
            for (int j = 0; j < 4; ++j) {
                unsigned sft = (unsigned)((j & 1) * 16);
                float sc0 = f16b(((j < 2) ? sh0.x : sh0.y) >> sft) +
                            f16b(((j < 2) ? sl0.x : sl0.y) >> sft);
                float sc1 = f16b(((j < 2) ? sh1.x : sh1.y) >> sft) +
                            f16b(((j < 2) ? sl1.x : sl1.y) >> sft);
                float d_ = (j == 0) ? dv.x : (j == 1) ? dv.y : (j == 2) ? dv.z : dv.w;
                float v0 = ftanh(d_ * (a0[j] + sc0) + bi0);
                float v1 = ftanh(d_ * (a1[j] + sc1) + bi1);
                fa[j] = v0; fb[j] = v1;
                if (wx) {
                    int row = r0 + j;
                    if (row < 100) { xrows[row*36 + n0] = v0; xrows[row*36 + 16 + n0] = v1; }
                }
            }
        }
    };

    // ---- XW via MFMA (B from precomputed wp planes) ----
    auto XWm = [&](const unsigned* wh, const unsigned* wl) {
        if (wv < 7) {
            f32x4 c0 = {0.f,0.f,0.f,0.f}, c1 = {0.f,0.f,0.f,0.f};
            const int arow = (wv << 4) + (l64 & 15);
            const int kq   = (l64 >> 4) << 3;
            const int bn   = l64 & 15;
            f16x8 ah, al;
            if (arow < 100) {
                float av[8];
                float4 xa = *(const float4*)&xrows[arow*36 + kq];
                float4 xb = *(const float4*)&xrows[arow*36 + kq + 4];
                av[0]=xa.x; av[1]=xa.y; av[2]=xa.z; av[3]=xa.w;
                av[4]=xb.x; av[5]=xb.y; av[6]=xb.z; av[7]=xb.w;
                split8(av, ah, al);
            } else {
                #pragma unroll
                for (int j = 0; j < 8; ++j) { ah[j] = (_Float16)0.f; al[j] = (_Float16)0.f; }
            }
            f16x8 b0h = __builtin_bit_cast(f16x8, *(const uint4*)(wh + bn*16 + (kq>>1)));
            f16x8 b0l = __builtin_bit_cast(f16x8, *(const uint4*)(wl + bn*16 + (kq>>1)));
            f16x8 b1h = __builtin_bit_cast(f16x8, *(const uint4*)(wh + (bn+16)*16 + (kq>>1)));
            f16x8 b1l = __builtin_bit_cast(f16x8, *(const uint4*)(wl + (bn+16)*16 + (kq>>1)));
            c0 = __builtin_amdgcn_mfma_f32_16x16x32_f16(ah, b0h, c0, 0, 0, 0);
            c0 = __builtin_amdgcn_mfma_f32_16x16x32_f16(al, b0h, c0, 0, 0, 0);
            c0 = __builtin_amdgcn_mfma_f32_16x16x32_f16(ah, b0l, c0, 0, 0, 0);
            c1 = __builtin_amdgcn_mfma_f32_16x16x32_f16(ah, b1h, c1, 0, 0, 0);
            c1 = __builtin_amdgcn_mfma_f32_16x16x32_f16(al, b1h, c1, 0, 0, 0);
            c1 = __builtin_amdgcn_mfma_f32_16x16x32_f16(ah, b1l, c1, 0, 0, 0);
            const int r0 = (wv << 4) + ((l64 >> 4) << 2);
            float4 dv = *(const float4*)&dis[r0];
            packStore(c0, bn,      r0, dv);
            packStore(c1, bn + 16, r0, dv);
        }
    };

    f32x4 f1a, f1b, f2a, f2b, f3a, f3b;

    AGG(f1a, f1b, b1, true);        __syncthreads();
    XWm(wp + 4096, wp + 4608);      __syncthreads();   // W2
    AGG(f2a, f2b, b2, true);        __syncthreads();
    XWm(wp + 5120, wp + 5632);      __syncthreads();   // W3
    AGG(f3a, f3b, b3, false);

    // ---- L4 (32->1): t4[i] = dis_i * (x3 row . W4) via shfl reduce ----
    if (wv < 7) {
        float w4a = W4[l64 & 15], w4b = W4[16 + (l64 & 15)];
        int r0 = (wv << 4) + ((l64 >> 4) << 2);
        #pragma unroll
        for (int j = 0; j < 4; ++j) {
            float v = f3a[j] * w4a + f3b[j] * w4b;
            v += __shfl_xor(v, 1, 16); v += __shfl_xor(v, 2, 16);
            v += __shfl_xor(v, 4, 16); v += __shfl_xor(v, 8, 16);
            int row = r0 + j;
            if ((l64 & 15) == 0 && row < 100) t4[row] = v * dis[row];
        }
    }
    __syncthreads();

    // ---- pack t4 hi/lo; zero srank for rank phase ----
    if (tid < 64) {
        float a = (2*tid < 100) ? t4[2*tid] : 0.f;
        float b = (2*tid+1 < 100) ? t4[2*tid+1] : 0.f;
        _Float16 ah = (_Float16)a, bh = (_Float16)b;
        t4h[tid] = (unsigned)__builtin_bit_cast(unsigned short, ah) |
                   ((unsigned)__builtin_bit_cast(unsigned short, bh) << 16);
        t4l[tid] = packh2(a - (float)ah, b - (float)bh);
    }
    if (tid < 100) srank[tid] = 0;
    __syncthreads();

    // ---- L4 dot via MFMA (only B-col 0 real) + exact tanh (sort keys) ----
    if (wv < 7) {
        f32x4 c = {0.f,0.f,0.f,0.f};
        const unsigned* ab = cntP + ((wv << 4) + (l64 & 15)) * 68 + ((l64 >> 4) << 2);
        const int kq = (l64 >> 4) << 3;
        const bool bz = (l64 & 15) == 0;
        #pragma unroll
        for (int ks = 0; ks < 4; ++ks) {
            f16x8 av = __builtin_bit_cast(f16x8, *(const uint4*)(ab + ks*16));
            f16x8 bh, bl;
            if (bz) {
                bh = __builtin_bit_cast(f16x8, *(const uint4*)(t4h + ks*16 + (kq>>1)));
                bl = __builtin_bit_cast(f16x8, *(const uint4*)(t4l + ks*16 + (kq>>1)));
            } else {
                #pragma unroll
                for (int j = 0; j < 8; ++j) { bh[j] = (_Float16)0.f; bl[j] = (_Float16)0.f; }
            }
            c = __builtin_amdgcn_mfma_f32_16x16x32_f16(av, bh, c, 0, 0, 0);
            c = __builtin_amdgcn_mfma_f32_16x16x32_f16(av, bl, c, 0, 0, 0);
        }
        if (bz) {
            int r0 = (wv << 4) + ((l64 >> 4) << 2);
            #pragma unroll
            for (int j = 0; j < 4; ++j) {
                int row = r0 + j;
                if (row < 100) sX4[row] = tanhf(dis[row] * (c[j] + t4[row]) + b4[0]);
            }
        }
    }
    __syncthreads();

    // ---- rank (500 thr) + stage tail weights into dead cntP/planes LDS ----
    if (tid < 500) {
        int i = tid / 5, seg = tid - i * 5;
        float vi = sX4[i];
        int c = 0, jb = seg * 20;
        #pragma unroll
        for (int jo = 0; jo < 20; ++jo) {
            int j = jb + jo;
            float vj = sX4[j];
            c += (vj > vi) || (vj == vi && j < i);
        }
        atomicAdd(&srank[i], c);
    }
    for (int k = tid; k < 1552; k += 512) w5s[k] = w5[k];
    if (tid < 16)  b5s[tid] = b5[tid];
    for (int k = tid; k < 2560; k += 512) w6s[k] = w6[k];
    if (tid < 32)  b6s[tid] = b6[tid];
    for (int k = tid; k < 1280; k += 512) fw2s[k] = fw2[k];
    if (tid < 10)  fb2s[tid] = fb2[tid];
    __syncthreads();

    // ---- gather top-30 rows into pooled[30][100] directly from frags ----
    if (wv < 7) {
        int n0 = l64 & 15, r0 = (wv << 4) + ((l64 >> 4) << 2);
        #pragma unroll
        for (int j = 0; j < 4; ++j) {
            int row = r0 + j;
            if (row < 100) {
                int rk = srank[row];
                if (rk < KTOP_C) {
                    float* pr = pooled + rk * 100;
                    pr[n0]      = f1a[j]; pr[16 + n0] = f1b[j];
                    pr[32 + n0] = f2a[j]; pr[48 + n0] = f2b[j];
                    pr[64 + n0] = f3a[j]; pr[80 + n0] = f3b[j];
                    if (n0 == 0) pr[96] = sX4[row];
                }
            }
        }
    }
    __syncthreads();

    // ---- conv5 (97 -> 16) + ReLU (weights from LDS) ----
    if (tid < 480) {
        int l = tid >> 4, co = tid & 15;
        const float* pr = pooled + l * 100;
        const float* wr = w5s + co * 97;
        float acc = b5s[co];
        for (int c4 = 0; c4 < 96; c4 += 4) {
            const float4 pv = *(const float4*)&pr[c4];
            acc = fmaf(pv.x, wr[c4+0], fmaf(pv.y, wr[c4+1], fmaf(pv.z, wr[c4+2], fmaf(pv.w, wr[c4+3], acc))));
        }
        acc = fmaf(pr[96], wr[96], acc);
        s5[co * 30 + l] = fmaxf(acc, 0.f);
    }
    __syncthreads();

    // ---- maxpool(2,2) ----
    if (tid < 240) {
        int co = tid / 15, j = tid - co * 15;
        sPb[co * 15 + j] = fmaxf(s5[co * 30 + 2*j], s5[co * 30 + 2*j + 1]);
    }
    __syncthreads();

    // ---- conv6 (16 -> 32, k=5) + ReLU (weights from LDS) ----
    if (tid < 352) {
        int co = tid / 11, l = tid - co * 11;
        float acc = b6s[co];
        for (int ci = 0; ci < 16; ++ci) {
            const float* wr = w6s + (co * 16 + ci) * 5;
            const float* pr = sPb + ci * 15 + l;
            acc = fmaf(wr[0], pr[0], fmaf(wr[1], pr[1], fmaf(wr[2], pr[2],
                  fmaf(wr[3], pr[3], fmaf(wr[4], pr[4], acc)))));
        }
        s6[co * 11 + l] = fmaxf(acc, 0.f);
    }
    __syncthreads();

    // ---- fc1 (352 -> 128) + ReLU (fw1 stays global: 180 KB) ----
    {
        int j = tid & 127, part = tid >> 7;
        int ibeg = part * 88, iend = ibeg + 88;
        float acc = (part == 0) ? fb1[j] : 0.f;
        for (int i = ibeg; i < iend; ++i)
            acc = fmaf(s6[i], fw1[i * 128 + j], acc);
        sFc[part * 128 + j] = acc;
    }
    __syncthreads();
    if (tid < 128) {
        float v = sFc[tid] + sFc[128 + tid] + sFc[256 + tid] + sFc[384 + tid];
        sO1[tid] = fmaxf(v, 0.f);
    }
    __syncthreads();

    // ---- fc2 (128 -> 10) + log_softmax (weights from LDS) ----
    if (tid < 10) {
        float acc = fb2s[tid];
        for (int k = 0; k < 128; ++k)
            acc = fmaf(sO1[k], fw2s[k * 10 + tid], acc);
        sZ[tid] = acc;
    }
    __syncthreads();
    if (tid < 10) {
        float m = sZ[0];
        for (int c = 1; c < 10; ++c) m = fmaxf(m, sZ[c]);
        float se = 0.f;
        for (int c = 0; c < 10; ++c) se += expf(sZ[c] - m);
        out[g * 10 + tid] = sZ[tid] - m - logf(se);
    }
}

extern "C" void kernel_launch(void* const* d_in, const int* in_sizes, int n_in,
                              void* d_out, int out_size, void* d_ws, size_t ws_size,
                              hipStream_t stream) {
    const float* x   = (const float*)d_in[0];
    const int*   ei  = (const int*)d_in[1];
    const int*   src = ei;
    const int*   dst = ei + N_EDGES_C;
    const float* W1 = (const float*)d_in[3];  const float* b1 = (const float*)d_in[4];
    const float* W2 = (const float*)d_in[5];  const float* b2 = (const float*)d_in[6];
    const float* W3 = (const float*)d_in[7];  const float* b3 = (const float*)d_in[8];
    const float* W4 = (const float*)d_in[9];  const float* b4 = (const float*)d_in[10];
    const float* w5 = (const float*)d_in[11]; const float* b5 = (const float*)d_in[12];
    const float* w6 = (const float*)d_in[13]; const float* b6 = (const float*)d_in[14];
    const float* fw1 = (const float*)d_in[15]; const float* fb1 = (const float*)d_in[16];
    const float* fw2 = (const float*)d_in[17]; const float* fb2 = (const float*)d_in[18];
    float* out = (float*)d_out;

    int* gcur = (int*)d_ws;
    unsigned short* slots = (unsigned short*)((char*)d_ws + 4096);
    unsigned* wpp = (unsigned*)((char*)d_ws + 4096 + (size_t)N_GRAPHS_C * CAP * 2);

    hipMemsetAsync(gcur, 0, 4096, stream);

    bucket_kernel<<<(N_EDGES_C + 8191) / 8192, 1024, 0, stream>>>(src, dst, gcur, slots);
    wprep_kernel<<<1, 512, 0, stream>>>(W1, W2, W3, wpp);

    size_t smem = (size_t)SMEM_WORDS * sizeof(unsigned);  // 64,448 B -> 2 blocks/CU
    hipFuncSetAttribute((const void*)dgcnn_kernel,
                        hipFuncAttributeMaxDynamicSharedMemorySize, (int)smem);
    dgcnn_kernel<<<N_GRAPHS_C, 512, smem, stream>>>(
        x, gcur, slots, wpp, b1, b2, b3, W4, b4,
        w5, b5, w6, b6, fw1, fb1, fw2, fb2, out);
}

// Round 15
// 106.010 us; speedup vs baseline: 4.2140x; 1.0384x over previous
//
#include <hip/hip_runtime.h>

#define N_GRAPHS_C 1000
#define NPG_C      100
#define N_EDGES_C  3200000
#define KTOP_C     30
#define CAP        4096      // per-graph edge-slot capacity (mean 3200, sigma ~57)
#define NB_BUCKET  391       // edge blocks; block NB_BUCKET does wprep

typedef _Float16 f16x8 __attribute__((ext_vector_type(8)));
typedef float    f32x4 __attribute__((ext_vector_type(4)));

__device__ __forceinline__ unsigned packh2(float x, float y) {
    _Float16 hx = (_Float16)x, hy = (_Float16)y;
    return (unsigned)__builtin_bit_cast(unsigned short, hx) |
           ((unsigned)__builtin_bit_cast(unsigned short, hy) << 16);
}

__device__ __forceinline__ float f16b(unsigned v) {
    return (float)__builtin_bit_cast(_Float16, (unsigned short)v);
}

__device__ __forceinline__ float ftanh(float x) {
    float e = __expf(2.0f * x);
    return 1.0f - 2.0f * __builtin_amdgcn_rcpf(e + 1.0f);
}

__device__ __forceinline__ void split8(const float* v, f16x8& h, f16x8& l) {
    #pragma unroll
    for (int j = 0; j < 8; ++j) {
        _Float16 hh = (_Float16)v[j];
        h[j] = hh;
        l[j] = (_Float16)(v[j] - (float)hh);
    }
}

// ---------------- workspace layout (bytes) ----------------
// [0, 4096)                 : gcur  int[1024]  (memset to 0)
// [4096, 8196096)           : slots u16[1000*4096]  packed edges (d<<7 | s)
// [8196096, +6144 words)    : wp — f16 hi/lo planes of W1/W2/W3
//   wp[0..2048) W1hi [32][64]   wp[2048..4096) W1lo
//   wp[4096..4608) W2hi [32][16] wp[4608..5120) W2lo
//   wp[5120..5632) W3hi          wp[5632..6144) W3lo

__global__ __launch_bounds__(1024)
void bucket_kernel(const int* __restrict__ src, const int* __restrict__ dst,
                   int* __restrict__ gcur, unsigned short* __restrict__ slots,
                   const float* __restrict__ W1, const float* __restrict__ W2,
                   const float* __restrict__ W3, unsigned* __restrict__ wp) {
    const int tid = threadIdx.x;
    if (blockIdx.x == NB_BUCKET) {
        // ---- wprep: pack W1/W2/W3 into f16 hi/lo B-plane layouts ----
        for (int w = tid; w < 2048; w += 1024) {
            int n = w >> 6, kp = w & 63, k = kp * 2;
            float a = W1[k*32 + n], b = W1[(k+1)*32 + n];
            _Float16 ah = (_Float16)a, bh = (_Float16)b;
            wp[w]        = (unsigned)__builtin_bit_cast(unsigned short, ah) |
                           ((unsigned)__builtin_bit_cast(unsigned short, bh) << 16);
            wp[2048 + w] = packh2(a - (float)ah, b - (float)bh);
        }
        for (int w = tid; w < 512; w += 1024) {
            int n = w >> 4, kp = w & 15, k = kp * 2;
            float a = W2[k*32 + n], b = W2[(k+1)*32 + n];
            _Float16 ah = (_Float16)a, bh = (_Float16)b;
            wp[4096 + w] = (unsigned)__builtin_bit_cast(unsigned short, ah) |
                           ((unsigned)__builtin_bit_cast(unsigned short, bh) << 16);
            wp[4608 + w] = packh2(a - (float)ah, b - (float)bh);
            float a3 = W3[k*32 + n], b3v = W3[(k+1)*32 + n];
            _Float16 a3h = (_Float16)a3, b3h = (_Float16)b3v;
            wp[5120 + w] = (unsigned)__builtin_bit_cast(unsigned short, a3h) |
                           ((unsigned)__builtin_bit_cast(unsigned short, b3h) << 16);
            wp[5632 + w] = packh2(a3 - (float)a3h, b3v - (float)b3h);
        }
        return;
    }

    __shared__ int hist[N_GRAPHS_C];
    const int base = blockIdx.x * 8192;
    for (int i = tid; i < N_GRAPHS_C; i += 1024) hist[i] = 0;
    __syncthreads();

    int g[8]; unsigned short pk[8]; bool v[8];
    #pragma unroll
    for (int k = 0; k < 8; ++k) {
        int e = base + tid + k * 1024;
        v[k] = false;
        if (e < N_EDGES_C) {
            int s = src[e], d = dst[e];
            if (s != d) {
                int gg = s / NPG_C;
                g[k] = gg;
                pk[k] = (unsigned short)(((d - gg * NPG_C) << 7) | (s - gg * NPG_C));
                v[k] = true;
                atomicAdd(&hist[gg], 1);
            }
        }
    }
    __syncthreads();
    for (int i = tid; i < N_GRAPHS_C; i += 1024) {
        int c = hist[i];
        hist[i] = atomicAdd(&gcur[i], c);
    }
    __syncthreads();
    #pragma unroll
    for (int k = 0; k < 8; ++k) {
        if (v[k]) {
            int pos = atomicAdd(&hist[g[k]], 1);
            if (pos < CAP) slots[g[k] * CAP + pos] = pk[k];
        }
    }
}

// ---------------- main per-graph kernel ----------------
// LDS (u32 word offsets), total 8496 words = 33,984 B -> 4 blocks/CU:
//  planes [0, 4352)     Td hi/lo planes ({hi,lo} x n(0..31) x 68 words);
//                       scatter u8[100][104] = first 2600 words (pre-L1 only)
//  xrows  [4352, 7952)  f32[100][36]; pooled[30][100] aliases after GCN
//  dis    [7952, 8064)  f32[112] (pads 0)
//  t4     [8064, 8168)  f32[104]
//  t4h    [8168, 8232)  t4l [8232, 8296)
//  sX4    [8296, 8396)  srank [8396, 8496)  (srank = rowsum early, rank late)
//  tail bufs s5..sZ (1728 f32) alias planes (dead after AGG3)
#define SMEM_WORDS 8496

extern "C" __global__ __launch_bounds__(512, 8)
void dgcnn_kernel(const float* __restrict__ x,
                  const int* __restrict__ gcur, const unsigned short* __restrict__ slots,
                  const unsigned* __restrict__ wp,
                  const float* __restrict__ b1, const float* __restrict__ b2,
                  const float* __restrict__ b3,
                  const float* __restrict__ W4, const float* __restrict__ b4,
                  const float* __restrict__ w5, const float* __restrict__ b5,
                  const float* __restrict__ w6, const float* __restrict__ b6,
                  const float* __restrict__ fw1, const float* __restrict__ fb1,
                  const float* __restrict__ fw2, const float* __restrict__ fb2,
                  float* __restrict__ out)
{
    extern __shared__ unsigned smu[];
    unsigned* planes = smu;                    // 4352
    float* xrows  = (float*)(smu + 4352);      // 3600, stride 36
    float* pooled = (float*)(smu + 4352);      // [30][100] aliases xrows (dead)
    float* dis = (float*)(smu + 7952);         // 112
    float* t4  = (float*)(smu + 8064);         // 104
    unsigned* t4h = smu + 8168;                // 64
    unsigned* t4l = smu + 8232;                // 64
    float* sX4 = (float*)(smu + 8296);         // 100
    int*   srank = (int*)(smu + 8396);         // 100
    float* s5  = (float*)smu;                  // tail bufs alias planes
    float* sPb = s5 + 480;
    float* s6  = s5 + 720;
    float* sO1 = s5 + 1072;
    float* sFc = s5 + 1200;
    float* sZ  = s5 + 1712;

    const int tid = threadIdx.x;
    const int g   = blockIdx.x;
    const int l64 = tid & 63;
    const int wv  = tid >> 6;                  // 0..7

    const float* xg = x + (size_t)g * NPG_C * 128;
    const unsigned* w1h = wp;
    const unsigned* w1l = wp + 2048;

    // ---- P0: zero scatter area; dis pads; rowsum accumulator ----
    for (int idx = tid; idx < 2600; idx += 512) planes[idx] = 0u;
    if (tid < 12) dis[100 + tid] = 0.f;
    if (tid < 100) srank[tid] = 0;
    __syncthreads();

    // ---- P1: scatter u8 counts (u8[100][104], row stride 26 words) ----
    {
        int ec = gcur[g]; if (ec > CAP) ec = CAP;
        for (int k = tid; k < ec; k += 512) {
            unsigned e = slots[g * CAP + k];
            unsigned idx = (e >> 7) * 104 + (e & 127);
            atomicAdd(&planes[idx >> 2], 1u << ((idx & 3) * 8));
        }
    }
    __syncthreads();

    // ---- P2: wave-parallel rowsums + cnt A-frags -> registers ----
    if (tid < 400) {
        int row = tid >> 2, part = tid & 3;
        int wb = part * 7, we = (part == 3) ? 26 : wb + 7;
        const unsigned* rw = planes + row * 26;
        unsigned s = 0;
        for (int k = wb; k < we; ++k) {
            unsigned v = rw[k];
            s += (v & 0xffu) + ((v >> 8) & 0xffu) + ((v >> 16) & 0xffu) + (v >> 24);
        }
        atomicAdd(&srank[row], (int)s);
    }
    f16x8 afr[4];
    {
        const int arow = (wv << 4) + (l64 & 15);
        if (wv < 7 && arow < 100) {
            const unsigned* cb = planes + arow * 26 + ((l64 >> 4) << 1);
            #pragma unroll
            for (int ks = 0; ks < 4; ++ks) {
                uint2 cw = *(const uint2*)(cb + ks * 8);
                #pragma unroll
                for (int j = 0; j < 4; ++j) {
                    afr[ks][j]     = (_Float16)(float)((cw.x >> (8*j)) & 255u);
                    afr[ks][4 + j] = (_Float16)(float)((cw.y >> (8*j)) & 255u);
                }
            }
        } else {
            #pragma unroll
            for (int ks = 0; ks < 4; ++ks)
                #pragma unroll
                for (int j = 0; j < 8; ++j) afr[ks][j] = (_Float16)0.f;
        }
    }
    __syncthreads();

    // ---- P3: dis = rsqrt(rowsum + 1) ----
    if (tid < 100) dis[tid] = rsqrtf((float)srank[tid] + 1.0f);
    __syncthreads();

    // ---- C-frag -> Td planes: v = c*dis, f16 hi/lo pairs, b64 stores ----
    auto packStore = [&](f32x4 c, int n, int r0, float4 dv) {
        float v0 = c[0]*dv.x, v1 = c[1]*dv.y, v2 = c[2]*dv.z, v3 = c[3]*dv.w;
        _Float16 h0=(_Float16)v0, h1=(_Float16)v1, h2=(_Float16)v2, h3=(_Float16)v3;
        uint2 wh, wl;
        wh.x = (unsigned)__builtin_bit_cast(unsigned short,h0) |
               ((unsigned)__builtin_bit_cast(unsigned short,h1) << 16);
        wh.y = (unsigned)__builtin_bit_cast(unsigned short,h2) |
               ((unsigned)__builtin_bit_cast(unsigned short,h3) << 16);
        wl.x = packh2(v0-(float)h0, v1-(float)h1);
        wl.y = packh2(v2-(float)h2, v3-(float)h3);
        *(uint2*)&planes[n*68 + (r0>>1)] = wh;
        *(uint2*)&planes[2176 + n*68 + (r0>>1)] = wl;
    };

    // ---- P4: zero plane pad words (56..67 per n, hi+lo); L1 = X@W1 MFMA ----
    for (int idx = tid; idx < 768; idx += 512) {
        int rw = idx / 12, wd = idx - rw * 12;
        planes[rw * 68 + 56 + wd] = 0u;
    }
    if (wv < 7) {
        f32x4 c0 = {0.f,0.f,0.f,0.f}, c1 = {0.f,0.f,0.f,0.f};
        const int arow = (wv << 4) + (l64 & 15);
        const int kq   = (l64 >> 4) << 3;
        const int bn   = l64 & 15;
        const bool aok = arow < 100;
        #pragma unroll
        for (int kc = 0; kc < 4; ++kc) {
            const int kb = (kc << 5) + kq;
            f16x8 ah, al;
            if (aok) {
                float av[8];
                float4 xa = *(const float4*)&xg[arow*128 + kb];
                float4 xb = *(const float4*)&xg[arow*128 + kb + 4];
                av[0]=xa.x; av[1]=xa.y; av[2]=xa.z; av[3]=xa.w;
                av[4]=xb.x; av[5]=xb.y; av[6]=xb.z; av[7]=xb.w;
                split8(av, ah, al);
            } else {
                #pragma unroll
                for (int j = 0; j < 8; ++j) { ah[j] = (_Float16)0.f; al[j] = (_Float16)0.f; }
            }
            f16x8 b0h = __builtin_bit_cast(f16x8, *(const uint4*)(w1h + bn*64 + (kb>>1)));
            f16x8 b0l = __builtin_bit_cast(f16x8, *(const uint4*)(w1l + bn*64 + (kb>>1)));
            f16x8 b1h = __builtin_bit_cast(f16x8, *(const uint4*)(w1h + (bn+16)*64 + (kb>>1)));
            f16x8 b1l = __builtin_bit_cast(f16x8, *(const uint4*)(w1l + (bn+16)*64 + (kb>>1)));
            c0 = __builtin_amdgcn_mfma_f32_16x16x32_f16(ah, b0h, c0, 0, 0, 0);
            c0 = __builtin_amdgcn_mfma_f32_16x16x32_f16(al, b0h, c0, 0, 0, 0);
            c0 = __builtin_amdgcn_mfma_f32_16x16x32_f16(ah, b0l, c0, 0, 0, 0);
            c1 = __builtin_amdgcn_mfma_f32_16x16x32_f16(ah, b1h, c1, 0, 0, 0);
            c1 = __builtin_amdgcn_mfma_f32_16x16x32_f16(al, b1h, c1, 0, 0, 0);
            c1 = __builtin_amdgcn_mfma_f32_16x16x32_f16(ah, b1l, c1, 0, 0, 0);
        }
        const int r0 = (wv << 4) + ((l64 >> 4) << 2);
        float4 dv = *(const float4*)&dis[r0];
        packStore(c0, bn,      r0, dv);
        packStore(c1, bn + 16, r0, dv);
    }
    __syncthreads();

    // ---- AGG via MFMA (A from registers) ----
    auto AGG = [&](f32x4& fa, f32x4& fb, const float* Bp, bool wx) {
        if (wv < 7) {
            f32x4 a0 = {0.f,0.f,0.f,0.f}, a1 = {0.f,0.f,0.f,0.f};
            const unsigned* bb = planes + (l64 & 15) * 68 + ((l64 >> 4) << 2);
            #pragma unroll
            for (int p = 0; p < 2; ++p) {
                const unsigned* bp = bb + p * 2176;
                #pragma unroll
                for (int ks = 0; ks < 4; ++ks) {
                    f16x8 b0 = __builtin_bit_cast(f16x8, *(const uint4*)(bp + ks*16));
                    f16x8 b1 = __builtin_bit_cast(f16x8, *(const uint4*)(bp + 16*68 + ks*16));
                    a0 = __builtin_amdgcn_mfma_f32_16x16x32_f16(afr[ks], b0, a0, 0, 0, 0);
                    a1 = __builtin_amdgcn_mfma_f32_16x16x32_f16(afr[ks], b1, a1, 0, 0, 0);
                }
            }
            int n0 = l64 & 15, r0 = (wv << 4) + ((l64 >> 4) << 2);
            uint2 sh0 = *(const uint2*)(planes + n0 * 68 + (r0 >> 1));
            uint2 sl0 = *(const uint2*)(planes + 2176 + n0 * 68 + (r0 >> 1));
            uint2 sh1 = *(const uint2*)(planes + (16 + n0) * 68 + (r0 >> 1));
            uint2 sl1 = *(const uint2*)(planes + 2176 + (16 + n0) * 68 + (r0 >> 1));
            float4 dv = *(const float4*)&dis[r0];
            float bi0 = Bp[n0], bi1 = Bp[16 + n0];
            #pragma unroll
            for (int j = 0; j < 4; ++j) {
                unsigned sft = (unsigned)((j & 1) * 16);
                float sc0 = f16b(((j < 2) ? sh0.x : sh0.y) >> sft) +
                            f16b(((j < 2) ? sl0.x : sl0.y) >> sft);
                float sc1 = f16b(((j < 2) ? sh1.x : sh1.y) >> sft) +
                            f16b(((j < 2) ? sl1.x : sl1.y) >> sft);
                float d_ = (j == 0) ? dv.x : (j == 1) ? dv.y : (j == 2) ? dv.z : dv.w;
                float v0 = ftanh(d_ * (a0[j] + sc0) + bi0);
                float v1 = ftanh(d_ * (a1[j] + sc1) + bi1);
                fa[j] = v0; fb[j] = v1;
                if (wx) {
                    int row = r0 + j;
                    if (row < 100) { xrows[row*36 + n0] = v0; xrows[row*36 + 16 + n0] = v1; }
                }
            }
        }
    };

    // ---- XW via MFMA (B from wp) ----
    auto XWm = [&](const unsigned* wh, const unsigned* wl) {
        if (wv < 7) {
            f32x4 c0 = {0.f,0.f,0.f,0.f}, c1 = {0.f,0.f,0.f,0.f};
            const int arow = (wv << 4) + (l64 & 15);
            const int kq   = (l64 >> 4) << 3;
            const int bn   = l64 & 15;
            f16x8 ah, al;
            if (arow < 100) {
                float av[8];
                float4 xa = *(const float4*)&xrows[arow*36 + kq];
                float4 xb = *(const float4*)&xrows[arow*36 + kq + 4];
                av[0]=xa.x; av[1]=xa.y; av[2]=xa.z; av[3]=xa.w;
                av[4]=xb.x; av[5]=xb.y; av[6]=xb.z; av[7]=xb.w;
                split8(av, ah, al);
            } else {
                #pragma unroll
                for (int j = 0; j < 8; ++j) { ah[j] = (_Float16)0.f; al[j] = (_Float16)0.f; }
            }
            f16x8 b0h = __builtin_bit_cast(f16x8, *(const uint4*)(wh + bn*16 + (kq>>1)));
            f16x8 b0l = __builtin_bit_cast(f16x8, *(const uint4*)(wl + bn*16 + (kq>>1)));
            f16x8 b1h = __builtin_bit_cast(f16x8, *(const uint4*)(wh + (bn+16)*16 + (kq>>1)));
            f16x8 b1l = __builtin_bit_cast(f16x8, *(const uint4*)(wl + (bn+16)*16 + (kq>>1)));
            c0 = __builtin_amdgcn_mfma_f32_16x16x32_f16(ah, b0h, c0, 0, 0, 0);
            c0 = __builtin_amdgcn_mfma_f32_16x16x32_f16(al, b0h, c0, 0, 0, 0);
            c0 = __builtin_amdgcn_mfma_f32_16x16x32_f16(ah, b0l, c0, 0, 0, 0);
            c1 = __builtin_amdgcn_mfma_f32_16x16x32_f16(ah, b1h, c1, 0, 0, 0);
            c1 = __builtin_amdgcn_mfma_f32_16x16x32_f16(al, b1h, c1, 0, 0, 0);
            c1 = __builtin_amdgcn_mfma_f32_16x16x32_f16(ah, b1l, c1, 0, 0, 0);
            const int r0 = (wv << 4) + ((l64 >> 4) << 2);
            float4 dv = *(const float4*)&dis[r0];
            packStore(c0, bn,      r0, dv);
            packStore(c1, bn + 16, r0, dv);
        }
    };

    f32x4 f1a, f1b, f2a, f2b, f3a, f3b;

    AGG(f1a, f1b, b1, true);        __syncthreads();
    XWm(wp + 4096, wp + 4608);      __syncthreads();   // W2
    AGG(f2a, f2b, b2, true);        __syncthreads();
    XWm(wp + 5120, wp + 5632);      __syncthreads();   // W3
    AGG(f3a, f3b, b3, false);

    // ---- L4 (32->1): t4[i] = dis_i * (x3 row . W4) via shfl reduce ----
    if (wv < 7) {
        float w4a = W4[l64 & 15], w4b = W4[16 + (l64 & 15)];
        int r0 = (wv << 4) + ((l64 >> 4) << 2);
        #pragma unroll
        for (int j = 0; j < 4; ++j) {
            float v = f3a[j] * w4a + f3b[j] * w4b;
            v += __shfl_xor(v, 1, 16); v += __shfl_xor(v, 2, 16);
            v += __shfl_xor(v, 4, 16); v += __shfl_xor(v, 8, 16);
            int row = r0 + j;
            if ((l64 & 15) == 0 && row < 100) t4[row] = v * dis[row];
        }
    }
    __syncthreads();

    // ---- pack t4 hi/lo; zero srank for rank phase ----
    if (tid < 64) {
        float a = (2*tid < 100) ? t4[2*tid] : 0.f;
        float b = (2*tid+1 < 100) ? t4[2*tid+1] : 0.f;
        _Float16 ah = (_Float16)a, bh = (_Float16)b;
        t4h[tid] = (unsigned)__builtin_bit_cast(unsigned short, ah) |
                   ((unsigned)__builtin_bit_cast(unsigned short, bh) << 16);
        t4l[tid] = packh2(a - (float)ah, b - (float)bh);
    }
    if (tid < 100) srank[tid] = 0;
    __syncthreads();

    // ---- L4 dot via MFMA (A from registers; only B-col 0 real) ----
    if (wv < 7) {
        f32x4 c = {0.f,0.f,0.f,0.f};
        const int kq2 = (l64 >> 4) << 2;
        const bool bz = (l64 & 15) == 0;
        #pragma unroll
        for (int ks = 0; ks < 4; ++ks) {
            f16x8 bh, bl;
            if (bz) {
                bh = __builtin_bit_cast(f16x8, *(const uint4*)(t4h + ks*16 + kq2));
                bl = __builtin_bit_cast(f16x8, *(const uint4*)(t4l + ks*16 + kq2));
            } else {
                #pragma unroll
                for (int j = 0; j < 8; ++j) { bh[j] = (_Float16)0.f; bl[j] = (_Float16)0.f; }
            }
            c = __builtin_amdgcn_mfma_f32_16x16x32_f16(afr[ks], bh, c, 0, 0, 0);
            c = __builtin_amdgcn_mfma_f32_16x16x32_f16(afr[ks], bl, c, 0, 0, 0);
        }
        if (bz) {
            int r0 = (wv << 4) + ((l64 >> 4) << 2);
            #pragma unroll
            for (int j = 0; j < 4; ++j) {
                int row = r0 + j;
                if (row < 100) sX4[row] = tanhf(dis[row] * (c[j] + t4[row]) + b4[0]);
            }
        }
    }
    __syncthreads();

    // ---- stable rank (value desc, index asc), wave-parallel ----
    if (tid < 500) {
        int i = tid / 5, seg = tid - i * 5;
        float vi = sX4[i];
        int c = 0, jb = seg * 20;
        #pragma unroll
        for (int jo = 0; jo < 20; ++jo) {
            int j = jb + jo;
            float vj = sX4[j];
            c += (vj > vi) || (vj == vi && j < i);
        }
        atomicAdd(&srank[i], c);
    }
    __syncthreads();

    // ---- gather top-30 rows into pooled[30][100] from frags ----
    if (wv < 7) {
        int n0 = l64 & 15, r0 = (wv << 4) + ((l64 >> 4) << 2);
        #pragma unroll
        for (int j = 0; j < 4; ++j) {
            int row = r0 + j;
            if (row < 100) {
                int rk = srank[row];
                if (rk < KTOP_C) {
                    float* pr = pooled + rk * 100;
                    pr[n0]      = f1a[j]; pr[16 + n0] = f1b[j];
                    pr[32 + n0] = f2a[j]; pr[48 + n0] = f2b[j];
                    pr[64 + n0] = f3a[j]; pr[80 + n0] = f3b[j];
                    if (n0 == 0) pr[96] = sX4[row];
                }
            }
        }
    }
    __syncthreads();

    // ---- conv5 (97 -> 16) + ReLU ----
    if (tid < 480) {
        int l = tid >> 4, co = tid & 15;
        const float* pr = pooled + l * 100;
        const float* wr = w5 + co * 97;
        float acc = b5[co];
        for (int c4 = 0; c4 < 96; c4 += 4) {
            const float4 pv = *(const float4*)&pr[c4];
            acc = fmaf(pv.x, wr[c4+0], fmaf(pv.y, wr[c4+1], fmaf(pv.z, wr[c4+2], fmaf(pv.w, wr[c4+3], acc))));
        }
        acc = fmaf(pr[96], wr[96], acc);
        s5[co * 30 + l] = fmaxf(acc, 0.f);
    }
    __syncthreads();

    // ---- maxpool(2,2) ----
    if (tid < 240) {
        int co = tid / 15, j = tid - co * 15;
        sPb[co * 15 + j] = fmaxf(s5[co * 30 + 2*j], s5[co * 30 + 2*j + 1]);
    }
    __syncthreads();

    // ---- conv6 (16 -> 32, k=5) + ReLU ----
    if (tid < 352) {
        int co = tid / 11, l = tid - co * 11;
        float acc = b6[co];
        for (int ci = 0; ci < 16; ++ci) {
            const float* wr = w6 + (co * 16 + ci) * 5;
            const float* pr = sPb + ci * 15 + l;
            acc = fmaf(wr[0], pr[0], fmaf(wr[1], pr[1], fmaf(wr[2], pr[2],
                  fmaf(wr[3], pr[3], fmaf(wr[4], pr[4], acc)))));
        }
        s6[co * 11 + l] = fmaxf(acc, 0.f);
    }
    __syncthreads();

    // ---- fc1 (352 -> 128) + ReLU ----
    {
        int j = tid & 127, part = tid >> 7;
        int ibeg = part * 88, iend = ibeg + 88;
        float acc = (part == 0) ? fb1[j] : 0.f;
        for (int i = ibeg; i < iend; ++i)
            acc = fmaf(s6[i], fw1[i * 128 + j], acc);
        sFc[part * 128 + j] = acc;
    }
    __syncthreads();
    if (tid < 128) {
        float v = sFc[tid] + sFc[128 + tid] + sFc[256 + tid] + sFc[384 + tid];
        sO1[tid] = fmaxf(v, 0.f);
    }
    __syncthreads();

    // ---- fc2 (128 -> 10) + log_softmax ----
    if (tid < 10) {
        float acc = fb2[tid];
        for (int k = 0; k < 128; ++k)
            acc = fmaf(sO1[k], fw2[k * 10 + tid], acc);
        sZ[tid] = acc;
    }
    __syncthreads();
    if (tid < 10) {
        float m = sZ[0];
        for (int c = 1; c < 10; ++c) m = fmaxf(m, sZ[c]);
        float se = 0.f;
        for (int c = 0; c < 10; ++c) se += expf(sZ[c] - m);
        out[g * 10 + tid] = sZ[tid] - m - logf(se);
    }
}

extern "C" void kernel_launch(void* const* d_in, const int* in_sizes, int n_in,
                              void* d_out, int out_size, void* d_ws, size_t ws_size,
                              hipStream_t stream) {
    const float* x   = (const float*)d_in[0];
    const int*   ei  = (const int*)d_in[1];
    const int*   src = ei;
    const int*   dst = ei + N_EDGES_C;
    const float* W1 = (const float*)d_in[3];  const float* b1 = (const float*)d_in[4];
    const float* W2 = (const float*)d_in[5];  const float* b2 = (const float*)d_in[6];
    const float* W3 = (const float*)d_in[7];  const float* b3 = (const float*)d_in[8];
    const float* W4 = (const float*)d_in[9];  const float* b4 = (const float*)d_in[10];
    const float* w5 = (const float*)d_in[11]; const float* b5 = (const float*)d_in[12];
    const float* w6 = (const float*)d_in[13]; const float* b6 = (const float*)d_in[14];
    const float* fw1 = (const float*)d_in[15]; const float* fb1 = (const float*)d_in[16];
    const float* fw2 = (const float*)d_in[17]; const float* fb2 = (const float*)d_in[18];
    float* out = (float*)d_out;

    int* gcur = (int*)d_ws;
    unsigned short* slots = (unsigned short*)((char*)d_ws + 4096);
    unsigned* wpp = (unsigned*)((char*)d_ws + 4096 + (size_t)N_GRAPHS_C * CAP * 2);

    hipMemsetAsync(gcur, 0, 4096, stream);

    bucket_kernel<<<NB_BUCKET + 1, 1024, 0, stream>>>(src, dst, gcur, slots,
                                                      W1, W2, W3, wpp);

    size_t smem = (size_t)SMEM_WORDS * sizeof(unsigned);  // 33,984 B -> 4 blocks/CU
    hipFuncSetAttribute((const void*)dgcnn_kernel,
                        hipFuncAttributeMaxDynamicSharedMemorySize, (int)smem);
    dgcnn_kernel<<<N_GRAPHS_C, 512, smem, stream>>>(
        x, gcur, slots, wpp, b1, b2, b3, W4, b4,
        w5, b5, w6, b6, fw1, fb1, fw2, fb2, out);
}

// Round 16
// 104.869 us; speedup vs baseline: 4.2598x; 1.0109x over previous
//
#include <hip/hip_runtime.h>

#define N_GRAPHS_C 1000
#define NPG_C      100
#define N_EDGES_C  3200000
#define KTOP_C     30
#define CAP        4096      // per-graph edge-slot capacity (mean 3200, sigma ~57)
#define NB_BUCKET  391       // edge blocks; block NB_BUCKET does wprep

typedef _Float16 f16x8 __attribute__((ext_vector_type(8)));
typedef float    f32x4 __attribute__((ext_vector_type(4)));

__device__ __forceinline__ unsigned packh2(float x, float y) {
    _Float16 hx = (_Float16)x, hy = (_Float16)y;
    return (unsigned)__builtin_bit_cast(unsigned short, hx) |
           ((unsigned)__builtin_bit_cast(unsigned short, hy) << 16);
}

__device__ __forceinline__ float f16b(unsigned v) {
    return (float)__builtin_bit_cast(_Float16, (unsigned short)v);
}

__device__ __forceinline__ float ftanh(float x) {
    float e = __expf(2.0f * x);
    return 1.0f - 2.0f * __builtin_amdgcn_rcpf(e + 1.0f);
}

__device__ __forceinline__ void split8(const float* v, f16x8& h, f16x8& l) {
    #pragma unroll
    for (int j = 0; j < 8; ++j) {
        _Float16 hh = (_Float16)v[j];
        h[j] = hh;
        l[j] = (_Float16)(v[j] - (float)hh);
    }
}

// ---------------- workspace layout (bytes) ----------------
// [0, 4096)                 : gcur  int[1024]  (memset to 0)
// [4096, 8196096)           : slots u16[1000*4096]  packed edges (d<<7 | s)
// [8196096, +6144 words)    : wp — f16 hi/lo planes of W1/W2/W3

__global__ __launch_bounds__(1024)
void bucket_kernel(const int* __restrict__ src, const int* __restrict__ dst,
                   int* __restrict__ gcur, unsigned short* __restrict__ slots,
                   const float* __restrict__ W1, const float* __restrict__ W2,
                   const float* __restrict__ W3, unsigned* __restrict__ wp) {
    const int tid = threadIdx.x;
    if (blockIdx.x == NB_BUCKET) {
        for (int w = tid; w < 2048; w += 1024) {
            int n = w >> 6, kp = w & 63, k = kp * 2;
            float a = W1[k*32 + n], b = W1[(k+1)*32 + n];
            _Float16 ah = (_Float16)a, bh = (_Float16)b;
            wp[w]        = (unsigned)__builtin_bit_cast(unsigned short, ah) |
                           ((unsigned)__builtin_bit_cast(unsigned short, bh) << 16);
            wp[2048 + w] = packh2(a - (float)ah, b - (float)bh);
        }
        for (int w = tid; w < 512; w += 1024) {
            int n = w >> 4, kp = w & 15, k = kp * 2;
            float a = W2[k*32 + n], b = W2[(k+1)*32 + n];
            _Float16 ah = (_Float16)a, bh = (_Float16)b;
            wp[4096 + w] = (unsigned)__builtin_bit_cast(unsigned short, ah) |
                           ((unsigned)__builtin_bit_cast(unsigned short, bh) << 16);
            wp[4608 + w] = packh2(a - (float)ah, b - (float)bh);
            float a3 = W3[k*32 + n], b3v = W3[(k+1)*32 + n];
            _Float16 a3h = (_Float16)a3, b3h = (_Float16)b3v;
            wp[5120 + w] = (unsigned)__builtin_bit_cast(unsigned short, a3h) |
                           ((unsigned)__builtin_bit_cast(unsigned short, b3h) << 16);
            wp[5632 + w] = packh2(a3 - (float)a3h, b3v - (float)b3h);
        }
        return;
    }

    __shared__ int hist[N_GRAPHS_C];
    const int base = blockIdx.x * 8192;
    for (int i = tid; i < N_GRAPHS_C; i += 1024) hist[i] = 0;
    __syncthreads();

    int g[8]; unsigned short pk[8]; bool v[8];
    #pragma unroll
    for (int k = 0; k < 8; ++k) {
        int e = base + tid + k * 1024;
        v[k] = false;
        if (e < N_EDGES_C) {
            int s = src[e], d = dst[e];
            if (s != d) {
                int gg = s / NPG_C;
                g[k] = gg;
                pk[k] = (unsigned short)(((d - gg * NPG_C) << 7) | (s - gg * NPG_C));
                v[k] = true;
                atomicAdd(&hist[gg], 1);
            }
        }
    }
    __syncthreads();
    for (int i = tid; i < N_GRAPHS_C; i += 1024) {
        int c = hist[i];
        hist[i] = atomicAdd(&gcur[i], c);
    }
    __syncthreads();
    #pragma unroll
    for (int k = 0; k < 8; ++k) {
        if (v[k]) {
            int pos = atomicAdd(&hist[g[k]], 1);
            if (pos < CAP) slots[g[k] * CAP + pos] = pk[k];
        }
    }
}

// ---------------- main per-graph kernel ----------------
// LDS (u32 word offsets), total 12848 words = 51,392 B -> 3 blocks/CU:
//  bufA   [0, 4352)       Td planes ping ({hi,lo} x n(0..31) x 68 words);
//                         scatter u8[100][104] = first 2600 words (pre-L1)
//  bufB   [4352, 8704)    Td planes pong
//  xrows  [8704, 12304)   f32[100][36]; pooled[30][100] aliases after GCN
//  dis    [12304, 12416)  f32[112] (pads 0)
//  t4     [12416, 12520)  f32[104]
//  t4h    [12520, 12584)  t4l [12584, 12648)
//  sX4    [12648, 12748)  srank [12748, 12848)
//  tail bufs sPb/s6/sO1/sFc/sZ (1248 f32) alias bufA (dead after AGG3)
#define SMEM_WORDS 12848

extern "C" __global__ __launch_bounds__(512, 6)
void dgcnn_kernel(const float* __restrict__ x,
                  const int* __restrict__ gcur, const unsigned short* __restrict__ slots,
                  const unsigned* __restrict__ wp,
                  const float* __restrict__ b1, const float* __restrict__ b2,
                  const float* __restrict__ b3,
                  const float* __restrict__ W4, const float* __restrict__ b4,
                  const float* __restrict__ w5, const float* __restrict__ b5,
                  const float* __restrict__ w6, const float* __restrict__ b6,
                  const float* __restrict__ fw1, const float* __restrict__ fb1,
                  const float* __restrict__ fw2, const float* __restrict__ fb2,
                  float* __restrict__ out)
{
    extern __shared__ unsigned smu[];
    unsigned* bufA = smu;                      // 4352
    unsigned* bufB = smu + 4352;               // 4352
    float* xrows  = (float*)(smu + 8704);      // 3600, stride 36
    float* pooled = (float*)(smu + 8704);      // [30][100] aliases xrows (dead)
    float* dis = (float*)(smu + 12304);        // 112
    float* t4  = (float*)(smu + 12416);        // 104
    unsigned* t4h = smu + 12520;               // 64
    unsigned* t4l = smu + 12584;               // 64
    float* sX4 = (float*)(smu + 12648);        // 100
    int*   srank = (int*)(smu + 12748);        // 100
    float* sPb = (float*)smu;                  // 240  (tail aliases bufA)
    float* s6  = (float*)smu + 240;            // 352
    float* sO1 = (float*)smu + 592;            // 128
    float* sFc = (float*)smu + 720;            // 512
    float* sZ  = (float*)smu + 1232;           // 16

    const int tid = threadIdx.x;
    const int g   = blockIdx.x;
    const int l64 = tid & 63;
    const int wv  = tid >> 6;                  // 0..7

    const float* xg = x + (size_t)g * NPG_C * 128;
    const unsigned* w1h = wp;
    const unsigned* w1l = wp + 2048;

    // ---- P0: zero scatter area; dis pads; rowsum accumulator ----
    for (int idx = tid; idx < 2600; idx += 512) bufA[idx] = 0u;
    if (tid < 12) dis[100 + tid] = 0.f;
    if (tid < 100) srank[tid] = 0;
    __syncthreads();

    // ---- P1: scatter u8 counts (u8[100][104], row stride 26 words) ----
    {
        int ec = gcur[g]; if (ec > CAP) ec = CAP;
        for (int k = tid; k < ec; k += 512) {
            unsigned e = slots[g * CAP + k];
            unsigned idx = (e >> 7) * 104 + (e & 127);
            atomicAdd(&bufA[idx >> 2], 1u << ((idx & 3) * 8));
        }
    }
    __syncthreads();

    // ---- P2: wave-parallel rowsums + cnt A-frags -> registers ----
    if (tid < 400) {
        int row = tid >> 2, part = tid & 3;
        int wb = part * 7, we = (part == 3) ? 26 : wb + 7;
        const unsigned* rw = bufA + row * 26;
        unsigned s = 0;
        for (int k = wb; k < we; ++k) {
            unsigned v = rw[k];
            s += (v & 0xffu) + ((v >> 8) & 0xffu) + ((v >> 16) & 0xffu) + (v >> 24);
        }
        atomicAdd(&srank[row], (int)s);
    }
    f16x8 afr[4];
    {
        const int arow = (wv << 4) + (l64 & 15);
        if (wv < 7 && arow < 100) {
            const unsigned* cb = bufA + arow * 26 + ((l64 >> 4) << 1);
            #pragma unroll
            for (int ks = 0; ks < 4; ++ks) {
                uint2 cw = *(const uint2*)(cb + ks * 8);
                #pragma unroll
                for (int j = 0; j < 4; ++j) {
                    afr[ks][j]     = (_Float16)(float)((cw.x >> (8*j)) & 255u);
                    afr[ks][4 + j] = (_Float16)(float)((cw.y >> (8*j)) & 255u);
                }
            }
        } else {
            #pragma unroll
            for (int ks = 0; ks < 4; ++ks)
                #pragma unroll
                for (int j = 0; j < 8; ++j) afr[ks][j] = (_Float16)0.f;
        }
    }
    __syncthreads();

    // ---- P3: dis = rsqrt(rowsum + 1) ----
    if (tid < 100) dis[tid] = rsqrtf((float)srank[tid] + 1.0f);
    __syncthreads();

    // ---- C-frag -> Td planes (target buffer) ----
    auto packStore = [&](unsigned* buf, f32x4 c, int n, int r0, float4 dv) {
        float v0 = c[0]*dv.x, v1 = c[1]*dv.y, v2 = c[2]*dv.z, v3 = c[3]*dv.w;
        _Float16 h0=(_Float16)v0, h1=(_Float16)v1, h2=(_Float16)v2, h3=(_Float16)v3;
        uint2 wh, wl;
        wh.x = (unsigned)__builtin_bit_cast(unsigned short,h0) |
               ((unsigned)__builtin_bit_cast(unsigned short,h1) << 16);
        wh.y = (unsigned)__builtin_bit_cast(unsigned short,h2) |
               ((unsigned)__builtin_bit_cast(unsigned short,h3) << 16);
        wl.x = packh2(v0-(float)h0, v1-(float)h1);
        wl.y = packh2(v2-(float)h2, v3-(float)h3);
        *(uint2*)&buf[n*68 + (r0>>1)] = wh;
        *(uint2*)&buf[2176 + n*68 + (r0>>1)] = wl;
    };

    // ---- P4: zero pad words in BOTH buffers; L1 = X@W1 MFMA -> bufA ----
    for (int idx = tid; idx < 1536; idx += 512) {
        int b = idx >> 9;                     // 0..2 -> covers 64 rows x 12 x 2 bufs
        int r = idx & 511;
        int rw = (b * 512 + r) / 12, wd = (b * 512 + r) % 12;
        if (rw < 64) bufA[rw * 68 + 56 + wd] = 0u; else bufB[(rw - 64) * 68 + 56 + wd] = 0u;
    }
    if (wv < 7) {
        f32x4 c0 = {0.f,0.f,0.f,0.f}, c1 = {0.f,0.f,0.f,0.f};
        const int arow = (wv << 4) + (l64 & 15);
        const int kq   = (l64 >> 4) << 3;
        const int bn   = l64 & 15;
        const bool aok = arow < 100;
        #pragma unroll
        for (int kc = 0; kc < 4; ++kc) {
            const int kb = (kc << 5) + kq;
            f16x8 ah, al;
            if (aok) {
                float av[8];
                float4 xa = *(const float4*)&xg[arow*128 + kb];
                float4 xb = *(const float4*)&xg[arow*128 + kb + 4];
                av[0]=xa.x; av[1]=xa.y; av[2]=xa.z; av[3]=xa.w;
                av[4]=xb.x; av[5]=xb.y; av[6]=xb.z; av[7]=xb.w;
                split8(av, ah, al);
            } else {
                #pragma unroll
                for (int j = 0; j < 8; ++j) { ah[j] = (_Float16)0.f; al[j] = (_Float16)0.f; }
            }
            f16x8 b0h = __builtin_bit_cast(f16x8, *(const uint4*)(w1h + bn*64 + (kb>>1)));
            f16x8 b0l = __builtin_bit_cast(f16x8, *(const uint4*)(w1l + bn*64 + (kb>>1)));
            f16x8 b1h = __builtin_bit_cast(f16x8, *(const uint4*)(w1h + (bn+16)*64 + (kb>>1)));
            f16x8 b1l = __builtin_bit_cast(f16x8, *(const uint4*)(w1l + (bn+16)*64 + (kb>>1)));
            c0 = __builtin_amdgcn_mfma_f32_16x16x32_f16(ah, b0h, c0, 0, 0, 0);
            c0 = __builtin_amdgcn_mfma_f32_16x16x32_f16(al, b0h, c0, 0, 0, 0);
            c0 = __builtin_amdgcn_mfma_f32_16x16x32_f16(ah, b0l, c0, 0, 0, 0);
            c1 = __builtin_amdgcn_mfma_f32_16x16x32_f16(ah, b1h, c1, 0, 0, 0);
            c1 = __builtin_amdgcn_mfma_f32_16x16x32_f16(al, b1h, c1, 0, 0, 0);
            c1 = __builtin_amdgcn_mfma_f32_16x16x32_f16(ah, b1l, c1, 0, 0, 0);
        }
        const int r0 = (wv << 4) + ((l64 >> 4) << 2);
        float4 dv = *(const float4*)&dis[r0];
        packStore(bufA, c0, bn,      r0, dv);
        packStore(bufA, c1, bn + 16, r0, dv);
    }
    __syncthreads();

    // ---- AGG via MFMA (A from registers; reads buf) ----
    auto AGG = [&](const unsigned* buf, f32x4& fa, f32x4& fb, const float* Bp, bool wx) {
        if (wv < 7) {
            f32x4 a0 = {0.f,0.f,0.f,0.f}, a1 = {0.f,0.f,0.f,0.f};
            const unsigned* bb = buf + (l64 & 15) * 68 + ((l64 >> 4) << 2);
            #pragma unroll
            for (int p = 0; p < 2; ++p) {
                const unsigned* bp = bb + p * 2176;
                #pragma unroll
                for (int ks = 0; ks < 4; ++ks) {
                    f16x8 b0 = __builtin_bit_cast(f16x8, *(const uint4*)(bp + ks*16));
                    f16x8 b1 = __builtin_bit_cast(f16x8, *(const uint4*)(bp + 16*68 + ks*16));
                    a0 = __builtin_amdgcn_mfma_f32_16x16x32_f16(afr[ks], b0, a0, 0, 0, 0);
                    a1 = __builtin_amdgcn_mfma_f32_16x16x32_f16(afr[ks], b1, a1, 0, 0, 0);
                }
            }
            int n0 = l64 & 15, r0 = (wv << 4) + ((l64 >> 4) << 2);
            uint2 sh0 = *(const uint2*)(buf + n0 * 68 + (r0 >> 1));
            uint2 sl0 = *(const uint2*)(buf + 2176 + n0 * 68 + (r0 >> 1));
            uint2 sh1 = *(const uint2*)(buf + (16 + n0) * 68 + (r0 >> 1));
            uint2 sl1 = *(const uint2*)(buf + 2176 + (16 + n0) * 68 + (r0 >> 1));
            float4 dv = *(const float4*)&dis[r0];
            float bi0 = Bp[n0], bi1 = Bp[16 + n0];
            #pragma unroll
            for (int j = 0; j < 4; ++j) {
                unsigned sft = (unsigned)((j & 1) * 16);
                float sc0 = f16b(((j < 2) ? sh0.x : sh0.y) >> sft) +
                            f16b(((j < 2) ? sl0.x : sl0.y) >> sft);
                float sc1 = f16b(((j < 2) ? sh1.x : sh1.y) >> sft) +
                            f16b(((j < 2) ? sl1.x : sl1.y) >> sft);
                float d_ = (j == 0) ? dv.x : (j == 1) ? dv.y : (j == 2) ? dv.z : dv.w;
                float v0 = ftanh(d_ * (a0[j] + sc0) + bi0);
                float v1 = ftanh(d_ * (a1[j] + sc1) + bi1);
                fa[j] = v0; fb[j] = v1;
                if (wx) {
                    int row = r0 + j;
                    if (row < 100) { xrows[row*36 + n0] = v0; xrows[row*36 + 16 + n0] = v1; }
                }
            }
        }
    };

    // ---- XW via MFMA: reads OWN-WAVE xrows rows (no barrier needed before),
    //      writes the OTHER plane buffer ----
    auto XWm = [&](unsigned* bufDst, const unsigned* wh, const unsigned* wl) {
        if (wv < 7) {
            f32x4 c0 = {0.f,0.f,0.f,0.f}, c1 = {0.f,0.f,0.f,0.f};
            const int arow = (wv << 4) + (l64 & 15);
            const int kq   = (l64 >> 4) << 3;
            const int bn   = l64 & 15;
            f16x8 ah, al;
            if (arow < 100) {
                float av[8];
                float4 xa = *(const float4*)&xrows[arow*36 + kq];
                float4 xb = *(const float4*)&xrows[arow*36 + kq + 4];
                av[0]=xa.x; av[1]=xa.y; av[2]=xa.z; av[3]=xa.w;
                av[4]=xb.x; av[5]=xb.y; av[6]=xb.z; av[7]=xb.w;
                split8(av, ah, al);
            } else {
                #pragma unroll
                for (int j = 0; j < 8; ++j) { ah[j] = (_Float16)0.f; al[j] = (_Float16)0.f; }
            }
            f16x8 b0h = __builtin_bit_cast(f16x8, *(const uint4*)(wh + bn*16 + (kq>>1)));
            f16x8 b0l = __builtin_bit_cast(f16x8, *(const uint4*)(wl + bn*16 + (kq>>1)));
            f16x8 b1h = __builtin_bit_cast(f16x8, *(const uint4*)(wh + (bn+16)*16 + (kq>>1)));
            f16x8 b1l = __builtin_bit_cast(f16x8, *(const uint4*)(wl + (bn+16)*16 + (kq>>1)));
            c0 = __builtin_amdgcn_mfma_f32_16x16x32_f16(ah, b0h, c0, 0, 0, 0);
            c0 = __builtin_amdgcn_mfma_f32_16x16x32_f16(al, b0h, c0, 0, 0, 0);
            c0 = __builtin_amdgcn_mfma_f32_16x16x32_f16(ah, b0l, c0, 0, 0, 0);
            c1 = __builtin_amdgcn_mfma_f32_16x16x32_f16(ah, b1h, c1, 0, 0, 0);
            c1 = __builtin_amdgcn_mfma_f32_16x16x32_f16(al, b1h, c1, 0, 0, 0);
            c1 = __builtin_amdgcn_mfma_f32_16x16x32_f16(ah, b1l, c1, 0, 0, 0);
            const int r0 = (wv << 4) + ((l64 >> 4) << 2);
            float4 dv = *(const float4*)&dis[r0];
            packStore(bufDst, c0, bn,      r0, dv);
            packStore(bufDst, c1, bn + 16, r0, dv);
        }
    };

    f32x4 f1a, f1b, f2a, f2b, f3a, f3b;

    AGG(bufA, f1a, f1b, b1, true);
    XWm(bufB, wp + 4096, wp + 4608);     // W2; no barrier: own-wave xrows, other buf
    __syncthreads();
    AGG(bufB, f2a, f2b, b2, true);
    XWm(bufA, wp + 5120, wp + 5632);     // W3
    __syncthreads();
    AGG(bufA, f3a, f3b, b3, false);

    // ---- L4 (32->1): t4[i] = dis_i * (x3 row . W4) via shfl reduce ----
    if (wv < 7) {
        float w4a = W4[l64 & 15], w4b = W4[16 + (l64 & 15)];
        int r0 = (wv << 4) + ((l64 >> 4) << 2);
        #pragma unroll
        for (int j = 0; j < 4; ++j) {
            float v = f3a[j] * w4a + f3b[j] * w4b;
            v += __shfl_xor(v, 1, 16); v += __shfl_xor(v, 2, 16);
            v += __shfl_xor(v, 4, 16); v += __shfl_xor(v, 8, 16);
            int row = r0 + j;
            if ((l64 & 15) == 0 && row < 100) t4[row] = v * dis[row];
        }
    }
    __syncthreads();

    // ---- pack t4 hi/lo; zero srank for rank phase ----
    if (tid < 64) {
        float a = (2*tid < 100) ? t4[2*tid] : 0.f;
        float b = (2*tid+1 < 100) ? t4[2*tid+1] : 0.f;
        _Float16 ah = (_Float16)a, bh = (_Float16)b;
        t4h[tid] = (unsigned)__builtin_bit_cast(unsigned short, ah) |
                   ((unsigned)__builtin_bit_cast(unsigned short, bh) << 16);
        t4l[tid] = packh2(a - (float)ah, b - (float)bh);
    }
    if (tid < 100) srank[tid] = 0;
    __syncthreads();

    // ---- L4 dot via MFMA (A from registers; only B-col 0 real) ----
    if (wv < 7) {
        f32x4 c = {0.f,0.f,0.f,0.f};
        const int kq2 = (l64 >> 4) << 2;
        const bool bz = (l64 & 15) == 0;
        #pragma unroll
        for (int ks = 0; ks < 4; ++ks) {
            f16x8 bh, bl;
            if (bz) {
                bh = __builtin_bit_cast(f16x8, *(const uint4*)(t4h + ks*16 + kq2));
                bl = __builtin_bit_cast(f16x8, *(const uint4*)(t4l + ks*16 + kq2));
            } else {
                #pragma unroll
                for (int j = 0; j < 8; ++j) { bh[j] = (_Float16)0.f; bl[j] = (_Float16)0.f; }
            }
            c = __builtin_amdgcn_mfma_f32_16x16x32_f16(afr[ks], bh, c, 0, 0, 0);
            c = __builtin_amdgcn_mfma_f32_16x16x32_f16(afr[ks], bl, c, 0, 0, 0);
        }
        if (bz) {
            int r0 = (wv << 4) + ((l64 >> 4) << 2);
            #pragma unroll
            for (int j = 0; j < 4; ++j) {
                int row = r0 + j;
                if (row < 100) sX4[row] = tanhf(dis[row] * (c[j] + t4[row]) + b4[0]);
            }
        }
    }
    __syncthreads();

    // ---- stable rank (value desc, index asc), wave-parallel ----
    if (tid < 500) {
        int i = tid / 5, seg = tid - i * 5;
        float vi = sX4[i];
        int c = 0, jb = seg * 20;
        #pragma unroll
        for (int jo = 0; jo < 20; ++jo) {
            int j = jb + jo;
            float vj = sX4[j];
            c += (vj > vi) || (vj == vi && j < i);
        }
        atomicAdd(&srank[i], c);
    }
    __syncthreads();

    // ---- gather top-30 rows into pooled[30][100] from frags ----
    if (wv < 7) {
        int n0 = l64 & 15, r0 = (wv << 4) + ((l64 >> 4) << 2);
        #pragma unroll
        for (int j = 0; j < 4; ++j) {
            int row = r0 + j;
            if (row < 100) {
                int rk = srank[row];
                if (rk < KTOP_C) {
                    float* pr = pooled + rk * 100;
                    pr[n0]      = f1a[j]; pr[16 + n0] = f1b[j];
                    pr[32 + n0] = f2a[j]; pr[48 + n0] = f2b[j];
                    pr[64 + n0] = f3a[j]; pr[80 + n0] = f3b[j];
                    if (n0 == 0) pr[96] = sX4[row];
                }
            }
        }
    }
    __syncthreads();

    // ---- conv5 (97 -> 16) + ReLU + maxpool(2,2), fused: [16][15] ----
    if (tid < 240) {
        int l2 = tid >> 4, co = tid & 15;      // l2: pooled slot 0..14
        const float* wr = w5 + co * 97;
        float accs[2];
        #pragma unroll
        for (int t = 0; t < 2; ++t) {
            const float* pr = pooled + (2*l2 + t) * 100;
            float acc = b5[co];
            for (int c4 = 0; c4 < 96; c4 += 4) {
                const float4 pv = *(const float4*)&pr[c4];
                acc = fmaf(pv.x, wr[c4+0], fmaf(pv.y, wr[c4+1], fmaf(pv.z, wr[c4+2], fmaf(pv.w, wr[c4+3], acc))));
            }
            accs[t] = fmaf(pr[96], wr[96], acc);
        }
        sPb[co * 15 + l2] = fmaxf(fmaxf(accs[0], accs[1]), 0.f);
    }
    __syncthreads();

    // ---- conv6 (16 -> 32, k=5) + ReLU: [32][11] ----
    if (tid < 352) {
        int co = tid / 11, l = tid - co * 11;
        float acc = b6[co];
        for (int ci = 0; ci < 16; ++ci) {
            const float* wr = w6 + (co * 16 + ci) * 5;
            const float* pr = sPb + ci * 15 + l;
            acc = fmaf(wr[0], pr[0], fmaf(wr[1], pr[1], fmaf(wr[2], pr[2],
                  fmaf(wr[3], pr[3], fmaf(wr[4], pr[4], acc)))));
        }
        s6[co * 11 + l] = fmaxf(acc, 0.f);
    }
    __syncthreads();

    // ---- fc1 (352 -> 128) + ReLU ----
    {
        int j = tid & 127, part = tid >> 7;
        int ibeg = part * 88, iend = ibeg + 88;
        float acc = (part == 0) ? fb1[j] : 0.f;
        for (int i = ibeg; i < iend; ++i)
            acc = fmaf(s6[i], fw1[i * 128 + j], acc);
        sFc[part * 128 + j] = acc;
    }
    __syncthreads();
    if (tid < 128) {
        float v = sFc[tid] + sFc[128 + tid] + sFc[256 + tid] + sFc[384 + tid];
        sO1[tid] = fmaxf(v, 0.f);
    }
    __syncthreads();

    // ---- fc2 (128 -> 10) + log_softmax ----
    if (tid < 10) {
        float acc = fb2[tid];
        for (int k = 0; k < 128; ++k)
            acc = fmaf(sO1[k], fw2[k * 10 + tid], acc);
        sZ[tid] = acc;
    }
    __syncthreads();
    if (tid < 10) {
        float m = sZ[0];
        for (int c = 1; c < 10; ++c) m = fmaxf(m, sZ[c]);
        float se = 0.f;
        for (int c = 0; c < 10; ++c) se += expf(sZ[c] - m);
        out[g * 10 + tid] = sZ[tid] - m - logf(se);
    }
}

extern "C" void kernel_launch(void* const* d_in, const int* in_sizes, int n_in,
                              void* d_out, int out_size, void* d_ws, size_t ws_size,
                              hipStream_t stream) {
    const float* x   = (const float*)d_in[0];
    const int*   ei  = (const int*)d_in[1];
    const int*   src = ei;
    const int*   dst = ei + N_EDGES_C;
    const float* W1 = (const float*)d_in[3];  const float* b1 = (const float*)d_in[4];
    const float* W2 = (const float*)d_in[5];  const float* b2 = (const float*)d_in[6];
    const float* W3 = (const float*)d_in[7];  const float* b3 = (const float*)d_in[8];
    const float* W4 = (const float*)d_in[9];  const float* b4 = (const float*)d_in[10];
    const float* w5 = (const float*)d_in[11]; const float* b5 = (const float*)d_in[12];
    const float* w6 = (const float*)d_in[13]; const float* b6 = (const float*)d_in[14];
    const float* fw1 = (const float*)d_in[15]; const float* fb1 = (const float*)d_in[16];
    const float* fw2 = (const float*)d_in[17]; const float* fb2 = (const float*)d_in[18];
    float* out = (float*)d_out;

    int* gcur = (int*)d_ws;
    unsigned short* slots = (unsigned short*)((char*)d_ws + 4096);
    unsigned* wpp = (unsigned*)((char*)d_ws + 4096 + (size_t)N_GRAPHS_C * CAP * 2);

    hipMemsetAsync(gcur, 0, 4096, stream);

    bucket_kernel<<<NB_BUCKET + 1, 1024, 0, stream>>>(src, dst, gcur, slots,
                                                      W1, W2, W3, wpp);

    size_t smem = (size_t)SMEM_WORDS * sizeof(unsigned);  // 51,392 B -> 3 blocks/CU
    hipFuncSetAttribute((const void*)dgcnn_kernel,
                        hipFuncAttributeMaxDynamicSharedMemorySize, (int)smem);
    dgcnn_kernel<<<N_GRAPHS_C, 512, smem, stream>>>(
        x, gcur, slots, wpp, b1, b2, b3, W4, b4,
        w5, b5, w6, b6, fw1, fb1, fw2, fb2, out);
}